// Round 9
// baseline (394.845 us; speedup 1.0000x reference)
//
#include <hip/hip_runtime.h>

// Problem constants (fixed by the reference)
#define Bb  2
#define Ss  2048
#define Dd  2048
#define HKV 8
#define QPK 4
#define HD  64
#define MR  (Bb * Ss)   // 4096 token rows
#define NQ  2048        // HQ*HD
#define NKV 512         // HKV*HD

#define LOG2E 1.4426950408889634f

typedef unsigned short u16;
typedef unsigned int u32;
typedef __attribute__((ext_vector_type(8))) short s16x8;   // 8 x bf16 (4 VGPRs)
typedef __attribute__((ext_vector_type(4))) float f32x4;   // MFMA accumulator

__device__ __forceinline__ u16 f2bf(float f) {
  unsigned u = __float_as_uint(f);
  u += 0x7fffu + ((u >> 16) & 1u);   // RNE; inputs finite
  return (u16)(u >> 16);
}

// async global->LDS, 16B per lane; LDS dest is wave-uniform base + lane*16
__device__ __forceinline__ void gload16(const u16* g, u16* l) {
  __builtin_amdgcn_global_load_lds(
      (const __attribute__((address_space(1))) unsigned int*)g,
      (__attribute__((address_space(3))) unsigned int*)l, 16, 0, 0);
}

// pack two f32 -> one dword of 2 bf16 (lo = a, hi = b)
__device__ __forceinline__ u32 cvtpk_bf16(float a, float b) {
  u32 r;
  asm volatile("v_cvt_pk_bf16_f32 %0, %1, %2" : "=v"(r) : "v"(a), "v"(b));
  return r;
}

#define BAR()    asm volatile("s_barrier" ::: "memory")
#define WAITV6() asm volatile("s_waitcnt vmcnt(6)" ::: "memory")
#define WAITV4() asm volatile("s_waitcnt vmcnt(4)" ::: "memory")
#define WAITV2() asm volatile("s_waitcnt vmcnt(2)" ::: "memory")
#define WAITV0() asm volatile("s_waitcnt vmcnt(0)" ::: "memory")

// ---------------------------------------------------------------------------
// LayerNorm: one block per row, fp32 in -> bf16 out
// ---------------------------------------------------------------------------
__global__ __launch_bounds__(256) void ln_kernel(
    const float* __restrict__ x, const float* __restrict__ g,
    const float* __restrict__ be, u16* __restrict__ xn)
{
  int row = blockIdx.x;
  int tid = threadIdx.x;
  const float4* xr = (const float4*)(x + (size_t)row * Dd);
  float4 a = xr[tid];
  float4 b4 = xr[tid + 256];
  float s  = a.x + a.y + a.z + a.w + b4.x + b4.y + b4.z + b4.w;
  float ss = a.x*a.x + a.y*a.y + a.z*a.z + a.w*a.w
           + b4.x*b4.x + b4.y*b4.y + b4.z*b4.z + b4.w*b4.w;
  #pragma unroll
  for (int off = 32; off > 0; off >>= 1) {
    s  += __shfl_down(s, off);
    ss += __shfl_down(ss, off);
  }
  __shared__ float red[8];
  int lane = tid & 63, w = tid >> 6;
  if (lane == 0) { red[w] = s; red[4 + w] = ss; }
  __syncthreads();
  s  = red[0] + red[1] + red[2] + red[3];
  ss = red[4] + red[5] + red[6] + red[7];
  float mu = s * (1.0f / Dd);
  float rs = rsqrtf(ss * (1.0f / Dd) - mu * mu + 1e-5f);

  u16* xo = xn + (size_t)row * Dd;
  const float4* gv4 = (const float4*)g;
  const float4* bv4 = (const float4*)be;
  #pragma unroll
  for (int p = 0; p < 2; ++p) {
    int idx = tid + p * 256;
    float4 xv = (p == 0) ? a : b4;
    float4 gg = gv4[idx], bb = bv4[idx];
    ushort4 pk;
    pk.x = f2bf((xv.x - mu) * rs * gg.x + bb.x);
    pk.y = f2bf((xv.y - mu) * rs * gg.y + bb.y);
    pk.z = f2bf((xv.z - mu) * rs * gg.z + bb.z);
    pk.w = f2bf((xv.w - mu) * rs * gg.w + bb.w);
    *(ushort4*)(xo + idx * 4) = pk;
  }
}

// ---------------------------------------------------------------------------
// Weight transpose + cast: W (K x N) fp32 -> WT (N x K) bf16
// ---------------------------------------------------------------------------
__global__ __launch_bounds__(256) void transpose_cast(
    const float* __restrict__ W, u16* __restrict__ WT, int K, int N)
{
  __shared__ float tile[32][33];
  int tx = threadIdx.x & 31, ty = threadIdx.x >> 5;  // ty 0..7
  int n0 = blockIdx.x * 32, k0 = blockIdx.y * 32;
  #pragma unroll
  for (int i = 0; i < 4; ++i)
    tile[ty + 8 * i][tx] = W[(size_t)(k0 + ty + 8 * i) * N + n0 + tx];
  __syncthreads();
  #pragma unroll
  for (int i = 0; i < 4; ++i)
    WT[(size_t)(n0 + ty + 8 * i) * K + k0 + tx] = f2bf(tile[tx][ty + 8 * i]);
}

// ---------------------------------------------------------------------------
// 256M x 128N deep-pipelined GEMM core.  512 threads = 8 waves (2M x 4N),
// per-wave output 128x32 (acc[8][2]).  BK=64.  TRIPLE-buffered A (3x32KB)
// and B (3x16KB) = 144 KB LDS: tile t stages A(t+2) (ph0/ph1) and B(t+2)
// (ph2); boundary vmcnt(6) drains A(t+1)+B(t+1) (issued a full tile earlier,
// ~7 phases of latency slack) and leaves A(t+2)+B(t+2) in flight.
// 16B-slot XOR swizzle (slot ^= row&7), linear dest + pre-swizzled source.
// ---------------------------------------------------------------------------
__device__ __forceinline__ void gemm3_core(
    const u16* __restrict__ A, const u16* __restrict__ BT, int K,
    int brow, int bcol, u16* __restrict__ As, u16* __restrict__ Bs,
    f32x4 (&acc)[8][2])
{
  const int tid  = threadIdx.x;
  const int lane = tid & 63;
  const int wave = tid >> 6;
  const int wr = wave >> 2, wc = wave & 3;
  const int m16 = lane & 15, quad = lane >> 4;
  const int NT = K >> 6;

  const int r0 = tid >> 3;                  // row within 64-row sweep
  const int sg = (tid & 7) ^ (r0 & 7);      // pre-swizzled source 16B-slot
  const u16* Asrc = A  + (size_t)(brow + r0) * K + sg * 8;
  const u16* Bsrc = BT + (size_t)(bcol + r0) * K + sg * 8;
  u16* AsW = As + wave * 512;
  u16* BsW = Bs + wave * 512;
  const size_t a64 = (size_t)64 * K;
  const size_t a128 = (size_t)128 * K;

  const int sl0 = (quad ^ (m16 & 7)) * 8;        // kh=0 read slot
  const int sl1 = ((quad | 4) ^ (m16 & 7)) * 8;  // kh=1 read slot
  const u16* Afr = As + wr * 8192 + m16 * 64;
  const u16* Bfr = Bs + (wc * 32 + m16) * 64;

  // ---- prologue: A(0),B(0),A(1),B(1) = 12 loads; drain tile 0 (vmcnt 6) ----
  #pragma unroll
  for (int h = 0; h < 2; ++h) {
    gload16(Asrc + h * a128, AsW + h * 8192);
    gload16(Asrc + h * a128 + a64, AsW + h * 8192 + 4096);
  }
  gload16(Bsrc, BsW);
  gload16(Bsrc + a64, BsW + 4096);
  #pragma unroll
  for (int h = 0; h < 2; ++h) {
    gload16(Asrc + h * a128 + 64, AsW + 16384 + h * 8192);
    gload16(Asrc + h * a128 + a64 + 64, AsW + 16384 + h * 8192 + 4096);
  }
  gload16(Bsrc + 64, BsW + 8192);
  gload16(Bsrc + a64 + 64, BsW + 8192 + 4096);
  WAITV6();
  BAR();

  for (int t = 0; t < NT; ++t) {
    const int bi = t % 3;
    const int bn = (t + 2) % 3;
    const u16* Abuf = Afr + bi * 16384;
    const u16* Bbuf = Bfr + bi * 8192;
    const bool st = (t + 2 < NT);
    const u16* Ag2 = Asrc + (size_t)(t + 2) * 64;
    const u16* Bg2 = Bsrc + (size_t)(t + 2) * 64;
    s16x8 bfr[2][2];
    #pragma unroll
    for (int ph = 0; ph < 4; ++ph) {
      s16x8 a0k0 = *(const s16x8*)(Abuf + (ph * 2 + 0) * 1024 + sl0);
      s16x8 a0k1 = *(const s16x8*)(Abuf + (ph * 2 + 0) * 1024 + sl1);
      s16x8 a1k0 = *(const s16x8*)(Abuf + (ph * 2 + 1) * 1024 + sl0);
      s16x8 a1k1 = *(const s16x8*)(Abuf + (ph * 2 + 1) * 1024 + sl1);
      if (ph == 0) {
        #pragma unroll
        for (int nj = 0; nj < 2; ++nj) {
          bfr[nj][0] = *(const s16x8*)(Bbuf + nj * 1024 + sl0);
          bfr[nj][1] = *(const s16x8*)(Bbuf + nj * 1024 + sl1);
        }
      }
      if (st) {
        if (ph == 0) {
          gload16(Ag2, AsW + bn * 16384);
          gload16(Ag2 + a64, AsW + bn * 16384 + 4096);
        } else if (ph == 1) {
          gload16(Ag2 + a128, AsW + bn * 16384 + 8192);
          gload16(Ag2 + a128 + a64, AsW + bn * 16384 + 8192 + 4096);
        } else if (ph == 2) {
          gload16(Bg2, BsW + bn * 8192);
          gload16(Bg2 + a64, BsW + bn * 8192 + 4096);
        }
      }
      BAR();
      __builtin_amdgcn_s_setprio(1);
      #pragma unroll
      for (int nj = 0; nj < 2; ++nj) {
        acc[ph*2+0][nj] = __builtin_amdgcn_mfma_f32_16x16x32_bf16(a0k0, bfr[nj][0], acc[ph*2+0][nj], 0, 0, 0);
        acc[ph*2+0][nj] = __builtin_amdgcn_mfma_f32_16x16x32_bf16(a0k1, bfr[nj][1], acc[ph*2+0][nj], 0, 0, 0);
        acc[ph*2+1][nj] = __builtin_amdgcn_mfma_f32_16x16x32_bf16(a1k0, bfr[nj][0], acc[ph*2+1][nj], 0, 0, 0);
        acc[ph*2+1][nj] = __builtin_amdgcn_mfma_f32_16x16x32_bf16(a1k1, bfr[nj][1], acc[ph*2+1][nj], 0, 0, 0);
      }
      __builtin_amdgcn_s_setprio(0);
      if (ph == 3) {
        if (st) WAITV6(); else WAITV0();
      }
      BAR();
    }
  }
}

// Fused QKV projection: BT = concat rows [WqT(2048) ; WkT(512) ; WvT(512)].
// 128-col tiles never straddle a region (2048, 2560 are multiples of 128).
// V region is written DIRECTLY TRANSPOSED into vT[(b*512+col)][t] (4
// consecutive t per lane -> ushort4), eliminating the transpose_v pass.
__global__ __launch_bounds__(512) void gemm3_qkv(
    const u16* __restrict__ A, const u16* __restrict__ BT,
    const float* __restrict__ bq, const float* __restrict__ bk,
    const float* __restrict__ bv,
    u16* __restrict__ qb, u16* __restrict__ kb, u16* __restrict__ vT)
{
  __shared__ u16 As[3 * 16384];   // 96 KB
  __shared__ u16 Bs[3 * 8192];    // 48 KB
  int nbx = 24;
  int id  = blockIdx.y * nbx + blockIdx.x;
  int nwg = 384;
  int swz = (id & 7) * (nwg >> 3) + (id >> 3);
  int bx = swz % nbx, by = swz / nbx;

  f32x4 acc[8][2] = {};
  gemm3_core(A, BT, Dd, by * 256, bx * 128, As, Bs, acc);

  int lane = threadIdx.x & 63, wave = threadIdx.x >> 6;
  int wr = wave >> 2, wc = wave & 3;
  int m16 = lane & 15, quad = lane >> 4;

  if (bx < 16) {          // ---- Q: rowmajor bf16, pre-scaled to base-2 ----
    int colb = bx * 128 + wc * 32;
    #pragma unroll
    for (int nj = 0; nj < 2; ++nj) {
      int col = colb + nj * 16 + m16;
      float bc = bq[col];
      #pragma unroll
      for (int mi = 0; mi < 8; ++mi)
        #pragma unroll
        for (int rr = 0; rr < 4; ++rr) {
          int row = by * 256 + wr * 128 + mi * 16 + quad * 4 + rr;
          qb[(size_t)row * NQ + col] = f2bf((acc[mi][nj][rr] + bc) * (0.125f * LOG2E));
        }
    }
  } else if (bx < 20) {   // ---- K: rowmajor bf16 ----
    int colb = (bx - 16) * 128 + wc * 32;
    #pragma unroll
    for (int nj = 0; nj < 2; ++nj) {
      int col = colb + nj * 16 + m16;
      float bc = bk[col];
      #pragma unroll
      for (int mi = 0; mi < 8; ++mi)
        #pragma unroll
        for (int rr = 0; rr < 4; ++rr) {
          int row = by * 256 + wr * 128 + mi * 16 + quad * 4 + rr;
          kb[(size_t)row * NKV + col] = f2bf(acc[mi][nj][rr] + bc);
        }
    }
  } else {                // ---- V: transposed write vT[(b*512+col)][t] ----
    int colb = (bx - 20) * 128 + wc * 32;
    #pragma unroll
    for (int nj = 0; nj < 2; ++nj) {
      int col = colb + nj * 16 + m16;
      float bc = bv[col];
      #pragma unroll
      for (int mi = 0; mi < 8; ++mi) {
        int row = by * 256 + wr * 128 + mi * 16 + quad * 4;   // 4 consecutive t
        int b = row >> 11, t = row & 2047;
        ushort4 pk;
        pk.x = f2bf(acc[mi][nj][0] + bc);
        pk.y = f2bf(acc[mi][nj][1] + bc);
        pk.z = f2bf(acc[mi][nj][2] + bc);
        pk.w = f2bf(acc[mi][nj][3] + bc);
        *(ushort4*)(vT + ((size_t)(b * NKV + col)) * Ss + t) = pk;
      }
    }
  }
}

// Wo projection: C(M,N) fp32 = A(M,K) @ BT(N,K)^T + bias; grid 16x16 = 1/CU.
__global__ __launch_bounds__(512) void gemm3_wo(
    const u16* __restrict__ A, const u16* __restrict__ BT,
    const float* __restrict__ bias, float* __restrict__ C, int N, int K)
{
  __shared__ u16 As[3 * 16384];   // 96 KB
  __shared__ u16 Bs[3 * 8192];    // 48 KB
  int nbx = N >> 7;                        // 16
  int id  = blockIdx.y * nbx + blockIdx.x;
  int nwg = gridDim.x * gridDim.y;         // 256
  int swz = (id & 7) * (nwg >> 3) + (id >> 3);
  int bx = swz % nbx, by = swz / nbx;

  f32x4 acc[8][2] = {};
  gemm3_core(A, BT, K, by * 256, bx * 128, As, Bs, acc);

  int lane = threadIdx.x & 63, wave = threadIdx.x >> 6;
  int wr = wave >> 2, wc = wave & 3;
  int m16 = lane & 15, quad = lane >> 4;
  int colb = bx * 128 + wc * 32;
  #pragma unroll
  for (int nj = 0; nj < 2; ++nj) {
    int col = colb + nj * 16 + m16;
    float bc = bias[col];
    #pragma unroll
    for (int mi = 0; mi < 8; ++mi)
      #pragma unroll
      for (int rr = 0; rr < 4; ++rr) {
        int row = by * 256 + wr * 128 + mi * 16 + quad * 4 + rr;
        C[(size_t)row * N + col] = acc[mi][nj][rr] + bc;
      }
  }
}

// ---------------------------------------------------------------------------
// Pass A: per-column softmax stats over the QUERY axis (base-2 domain).
// Writes cst NEGATED: cst[T] = -(m2 + log2 l), so pass B can fold it into
// the MFMA accumulator init (saves 16 v_sub per tile-wave there).
// ---------------------------------------------------------------------------
__global__ __launch_bounds__(256) void pass_a_mfma(
    const u16* __restrict__ qb, const u16* __restrict__ kb,
    float* __restrict__ cst)
{
  __shared__ u16 Qs[2][64 * 64];   // 16 KB
  int combo = blockIdx.x;
  int qk = combo & 3, bh = combo >> 2;
  int b = bh >> 3, h = bh & 7;
  int g = blockIdx.y;                     // 0..15, longest first
  int tid = threadIdx.x;
  int lane = tid & 63, wave = tid >> 6;
  int m16 = lane & 15, quad = lane >> 4;
  int T0w = g * 128 + wave * 32;          // wave's 32 T-columns

  const u16* kbase = kb + (size_t)b * Ss * NKV + h * HD;
  const u16* qbase = qb + (size_t)b * Ss * NQ + (h * QPK + qk) * HD;

  s16x8 kf[2][2];   // B-operand frags (n=T), loaded once
  #pragma unroll
  for (int jg = 0; jg < 2; ++jg)
    #pragma unroll
    for (int dc = 0; dc < 2; ++dc)
      kf[jg][dc] = *(const s16x8*)(kbase + (size_t)(T0w + jg * 16 + m16) * NKV + dc * 32 + quad * 8);

  float ms[2] = {-1e30f, -1e30f};
  float ls[2] = {0.f, 0.f};
  int srow  = (wave << 3) + (lane >> 3);
  int slot0 = (lane & 7) ^ (lane >> 3);
  int sl0 = quad ^ (m16 & 7);
  int sl1 = (quad | 4) ^ (m16 & 7);
  int tDiag = T0w & ~63;

  // prologue: stage tile t0 = g*128 into Qs[0]
  {
    u16* QsW = &Qs[0][(wave * 8) * 64];
    int t0 = g * 128;
    gload16(qbase + (size_t)(t0 + srow) * NQ + slot0 * 8, QsW);
    gload16(qbase + (size_t)(t0 + srow + 32) * NQ + slot0 * 8, QsW + 32 * 64);
  }

  for (int t0 = g * 128; t0 < Ss; t0 += 64) {
    int cur = (t0 >> 6) & 1;
    bool nxt = (t0 + 64 < Ss);
    if (nxt) {
      u16* QsW = &Qs[cur ^ 1][(wave * 8) * 64];
      gload16(qbase + (size_t)(t0 + 64 + srow) * NQ + slot0 * 8, QsW);
      gload16(qbase + (size_t)(t0 + 64 + srow + 32) * NQ + slot0 * 8, QsW + 32 * 64);
      WAITV2();
    } else {
      WAITV0();
    }
    BAR();
    if (t0 + 63 < T0w) { BAR(); continue; }   // wave inactive; barriers matched

    const u16* Qc = &Qs[cur][0];
    s16x8 af[4][2];
    #pragma unroll
    for (int i = 0; i < 4; ++i) {
      af[i][0] = *(const s16x8*)(Qc + (i * 16 + m16) * 64 + sl0 * 8);
      af[i][1] = *(const s16x8*)(Qc + (i * 16 + m16) * 64 + sl1 * 8);
    }
    f32x4 acc[4][2];
    #pragma unroll
    for (int i = 0; i < 4; ++i)
      #pragma unroll
      for (int jg = 0; jg < 2; ++jg) {
        f32x4 z = {};
        z = __builtin_amdgcn_mfma_f32_16x16x32_bf16(af[i][0], kf[jg][0], z, 0, 0, 0);
        acc[i][jg] = __builtin_amdgcn_mfma_f32_16x16x32_bf16(af[i][1], kf[jg][1], z, 0, 0, 0);
      }
    if (t0 == tDiag) {   // diagonal block: mask t < T with very-low sentinel
      #pragma unroll
      for (int i = 0; i < 4; ++i)
        #pragma unroll
        for (int jg = 0; jg < 2; ++jg) {
          int tg = t0 + i * 16 + quad * 4;
          int Tg = T0w + jg * 16 + m16;
          #pragma unroll
          for (int r = 0; r < 4; ++r)
            if (tg + r < Tg) acc[i][jg][r] = -3e38f;
        }
    }
    #pragma unroll
    for (int jg = 0; jg < 2; ++jg) {
      float bm = -3e38f;
      #pragma unroll
      for (int i = 0; i < 4; ++i)
        #pragma unroll
        for (int r = 0; r < 4; ++r) bm = fmaxf(bm, acc[i][jg][r]);
      float mn = fmaxf(ms[jg], bm);
      float se = 0.f;
      #pragma unroll
      for (int i = 0; i < 4; ++i)
        #pragma unroll
        for (int r = 0; r < 4; ++r) se += exp2f(acc[i][jg][r] - mn);
      ls[jg] = ls[jg] * exp2f(ms[jg] - mn) + se;
      ms[jg] = mn;
    }
    BAR();
  }
  // cross-quad merge (cols live on m16; quads hold disjoint t-subsets)
  #pragma unroll
  for (int jg = 0; jg < 2; ++jg) {
    float m = ms[jg], l = ls[jg];
    #pragma unroll
    for (int off = 16; off <= 32; off <<= 1) {
      float mo = __shfl_xor(m, off);
      float lo = __shfl_xor(l, off);
      float mn = fmaxf(m, mo);
      l = l * exp2f(m - mn) + lo * exp2f(mo - mn);
      m = mn;
    }
    if (quad == 0)
      cst[(size_t)(bh * QPK + qk) * Ss + T0w + jg * 16 + m16] = -(m + __log2f(l));
  }
}

// ---------------------------------------------------------------------------
// Pass B: out[t,:] = sum_{T<=t} exp2(s2(t,T)+negc[T]) * v[T,:]
// K AND V double-buffered in LDS (counted vmcnt(4)); negc folded into the
// QK MFMA accumulator init (cst is pre-negated by pass A) -> no per-element
// subtract.  P never touches LDS: cvt_pk_bf16 + permlane32/16 swaps.
// ---------------------------------------------------------------------------
__global__ __launch_bounds__(256) void pass_b_mfma(
    const u16* __restrict__ qb, const u16* __restrict__ kb,
    const u16* __restrict__ vT, const float* __restrict__ cst,
    u16* __restrict__ attn)
{
  __shared__ u16 Ks[2][64 * 64];   // 16 KB
  __shared__ u16 Vs[2][64 * 64];   // 16 KB
  int combo = blockIdx.x;
  int qk = combo & 3, bh = combo >> 2;
  int b = bh >> 3, h = bh & 7;
  int g = 31 - blockIdx.y;                // longest first
  int tid = threadIdx.x;
  int lane = tid & 63, wave = tid >> 6;
  int m16 = lane & 15, quad = lane >> 4;
  int trow = g * 64 + wave * 16;          // wave's 16 t-rows

  const u16* qbase = qb + (size_t)b * Ss * NQ + (h * QPK + qk) * HD;
  const u16* kbase = kb + (size_t)b * Ss * NKV + h * HD;
  const u16* vbase = vT + (size_t)(bh * 64) * Ss;
  const float* cbase = cst + (size_t)(bh * QPK + qk) * Ss;

  s16x8 qf[2];   // B-operand (n=t) frags for this wave's rows
  #pragma unroll
  for (int dc = 0; dc < 2; ++dc)
    qf[dc] = *(const s16x8*)(qbase + (size_t)(trow + m16) * NQ + dc * 32 + quad * 8);

  f32x4 oacc[4] = {};   // C-layout: row t = quad*4+r, col d = dj*16+m16
  int srow  = (wave << 3) + (lane >> 3);
  int slot0 = (lane & 7) ^ (lane >> 3);
  int sl0 = quad ^ (m16 & 7);
  int sl1 = (quad | 4) ^ (m16 & 7);
  int Tend = g * 64;

  // prologue: stage K+V tile 0 into buf 0
  {
    u16* KsW = &Ks[0][(wave * 8) * 64];
    u16* VsW = &Vs[0][(wave * 8) * 64];
    gload16(kbase + (size_t)srow * NKV + slot0 * 8, KsW);
    gload16(kbase + (size_t)(srow + 32) * NKV + slot0 * 8, KsW + 32 * 64);
    gload16(vbase + (size_t)srow * Ss + slot0 * 8, VsW);
    gload16(vbase + (size_t)(srow + 32) * Ss + slot0 * 8, VsW + 32 * 64);
  }

  for (int T0 = 0; T0 <= Tend; T0 += 64) {
    int cur = (T0 >> 6) & 1;
    bool nxt = (T0 + 64 <= Tend);
    // negc loads for THIS tile -- issued before next-tile stage (ordering
    // matters: compiler's wait-for-cc then leaves the stage loads in flight)
    float4 cc[4];
    #pragma unroll
    for (int i = 0; i < 4; ++i)
      cc[i] = *(const float4*)(cbase + T0 + i * 16 + quad * 4);
    __builtin_amdgcn_sched_barrier(0);
    if (nxt) {
      u16* KsW = &Ks[cur ^ 1][(wave * 8) * 64];
      u16* VsW = &Vs[cur ^ 1][(wave * 8) * 64];
      gload16(kbase + (size_t)(T0 + 64 + srow) * NKV + slot0 * 8, KsW);
      gload16(kbase + (size_t)(T0 + 64 + srow + 32) * NKV + slot0 * 8, KsW + 32 * 64);
      gload16(vbase + (size_t)srow * Ss + T0 + 64 + slot0 * 8, VsW);
      gload16(vbase + (size_t)(srow + 32) * Ss + T0 + 64 + slot0 * 8, VsW + 32 * 64);
      WAITV4();   // drains prev stage + cc; leaves the 4 new stage loads
    } else {
      WAITV0();
    }
    BAR();
    bool diag = (T0 == Tend);
    const u16* Kc = &Ks[cur][0];
    const u16* Vc = &Vs[cur][0];
    // tc = T-chunk of 32 (PV k-dim); i = score T-row-block of 16
    #pragma unroll
    for (int tc = 0; tc < 2; ++tc) {
      u32 A[2], Bw[2];
      #pragma unroll
      for (int ii = 0; ii < 2; ++ii) {
        int i = tc * 2 + ii;
        s16x8 k0 = *(const s16x8*)(Kc + (i * 16 + m16) * 64 + sl0 * 8);
        s16x8 k1 = *(const s16x8*)(Kc + (i * 16 + m16) * 64 + sl1 * 8);
        float4 c4 = cc[i];
        f32x4 z = {c4.x, c4.y, c4.z, c4.w};   // acc-init = -c (pre-negated)
        z = __builtin_amdgcn_mfma_f32_16x16x32_bf16(k0, qf[0], z, 0, 0, 0);
        z = __builtin_amdgcn_mfma_f32_16x16x32_bf16(k1, qf[1], z, 0, 0, 0);
        float w0 = exp2f(z[0]);
        float w1 = exp2f(z[1]);
        float w2 = exp2f(z[2]);
        float w3 = exp2f(z[3]);
        if (diag) {
          int t  = trow + m16;
          int Tg = T0 + i * 16 + quad * 4;
          if (Tg + 0 > t) w0 = 0.f;
          if (Tg + 1 > t) w1 = 0.f;
          if (Tg + 2 > t) w2 = 0.f;
          if (Tg + 3 > t) w3 = 0.f;
        }
        A[ii]  = cvtpk_bf16(w0, w1);
        Bw[ii] = cvtpk_bf16(w2, w3);
      }
      // cross-quad redistribution: quads {0,1}->dest {0,2}, {2,3}->dest {1,3}
      asm volatile("v_permlane32_swap_b32 %0, %1" : "+v"(A[0]),  "+v"(A[1]));
      asm volatile("v_permlane16_swap_b32 %0, %1" : "+v"(A[0]),  "+v"(A[1]));
      asm volatile("v_permlane32_swap_b32 %0, %1" : "+v"(Bw[0]), "+v"(Bw[1]));
      asm volatile("v_permlane16_swap_b32 %0, %1" : "+v"(Bw[0]), "+v"(Bw[1]));
      union { uint4 u; s16x8 v; } pu;
      pu.u.x = A[0]; pu.u.y = Bw[0]; pu.u.z = A[1]; pu.u.w = Bw[1];
      s16x8 pa = pu.v;   // A-operand: P[t=m16][T = T0 + tc*32 + quad*8 + j]
      #pragma unroll
      for (int dj = 0; dj < 4; ++dj) {
        int vsl = (quad | (tc << 2)) ^ (m16 & 7);
        s16x8 vf = *(const s16x8*)(Vc + (dj * 16 + m16) * 64 + vsl * 8);
        oacc[dj] = __builtin_amdgcn_mfma_f32_16x16x32_bf16(pa, vf, oacc[dj], 0, 0, 0);
      }
    }
    BAR();
  }
  // ---- epilogue: attn (b, t, (h*QPK+qk)*64 + d) bf16 ----
  u16* abase = attn + (size_t)b * Ss * NQ + (h * QPK + qk) * HD;
  #pragma unroll
  for (int dj = 0; dj < 4; ++dj)
    #pragma unroll
    for (int r = 0; r < 4; ++r)
      abase[(size_t)(trow + quad * 4 + r) * NQ + dj * 16 + m16] = f2bf(oacc[dj][r]);
}

// ---------------------------------------------------------------------------
extern "C" void kernel_launch(void* const* d_in, const int* in_sizes, int n_in,
                              void* d_out, int out_size, void* d_ws, size_t ws_size,
                              hipStream_t stream)
{
  (void)in_sizes; (void)n_in; (void)out_size; (void)ws_size;
  const float* x   = (const float*)d_in[0];
  const float* lng = (const float*)d_in[1];
  const float* lnb = (const float*)d_in[2];
  const float* Wq  = (const float*)d_in[3];
  const float* bq  = (const float*)d_in[4];
  const float* Wk  = (const float*)d_in[5];
  const float* bk  = (const float*)d_in[6];
  const float* Wv  = (const float*)d_in[7];
  const float* bv  = (const float*)d_in[8];
  const float* Wo  = (const float*)d_in[9];
  const float* bo  = (const float*)d_in[10];
  float* out = (float*)d_out;

  char* ws = (char*)d_ws;
  size_t off = 0;
  auto take = [&](size_t bytes) -> char* {
    char* p = ws + off;
    off += (bytes + 255) & ~(size_t)255;
    return p;
  };
  u16*    xnb   = (u16*)take((size_t)MR * Dd * 2);             // 16 MB
  u16*    wqkvT = (u16*)take((size_t)(NQ + 2 * NKV) * Dd * 2); // 12 MB (Q;K;V rows)
  u16*    woT   = (u16*)take((size_t)Dd * NQ * 2);             // 8 MB
  u16*    qbB   = (u16*)take((size_t)MR * NQ * 2);             // 16 MB
  u16*    kbB   = (u16*)take((size_t)MR * NKV * 2);            // 4 MB
  u16*    vTb   = (u16*)take((size_t)MR * NKV * 2);            // 4 MB (transposed)
  float*  cst   = (float*)take((size_t)Bb * HKV * QPK * Ss * 4); // 0.5 MB
  u16*    attnb = (u16*)take((size_t)MR * NQ * 2);             // 16 MB

  ln_kernel<<<MR, 256, 0, stream>>>(x, lng, lnb, xnb);
  // concatenated BT: rows [0,2048)=WqT, [2048,2560)=WkT, [2560,3072)=WvT
  transpose_cast<<<dim3(NQ / 32, Dd / 32), 256, 0, stream>>>(Wq, wqkvT, Dd, NQ);
  transpose_cast<<<dim3(NKV / 32, Dd / 32), 256, 0, stream>>>(Wk, wqkvT + (size_t)NQ * Dd, Dd, NKV);
  transpose_cast<<<dim3(NKV / 32, Dd / 32), 256, 0, stream>>>(Wv, wqkvT + (size_t)(NQ + NKV) * Dd, Dd, NKV);
  transpose_cast<<<dim3(NQ / 32, Dd / 32), 256, 0, stream>>>(Wo, woT, Dd, NQ);

  // fused Q/K/V projection (q pre-scaled; V written directly transposed)
  gemm3_qkv<<<dim3(24, 16), 512, 0, stream>>>(xnb, wqkvT, bq, bk, bv, qbB, kbB, vTb);

  pass_a_mfma<<<dim3(64, 16), 256, 0, stream>>>(qbB, kbB, cst);
  pass_b_mfma<<<dim3(64, 32), 256, 0, stream>>>(qbB, kbB, vTb, cst, attnb);

  gemm3_wo<<<dim3(16, 16), 512, 0, stream>>>(attnb, woT, bo, out, Dd, NQ);
}

// Round 10
// 381.992 us; speedup vs baseline: 1.0336x; 1.0336x over previous
//
#include <hip/hip_runtime.h>

// Problem constants (fixed by the reference)
#define Bb  2
#define Ss  2048
#define Dd  2048
#define HKV 8
#define QPK 4
#define HD  64
#define MR  (Bb * Ss)   // 4096 token rows
#define NQ  2048        // HQ*HD
#define NKV 512         // HKV*HD

#define LOG2E 1.4426950408889634f

typedef unsigned short u16;
typedef unsigned int u32;
typedef __attribute__((ext_vector_type(8))) short s16x8;   // 8 x bf16 (4 VGPRs)
typedef __attribute__((ext_vector_type(4))) float f32x4;   // MFMA accumulator

__device__ __forceinline__ u16 f2bf(float f) {
  unsigned u = __float_as_uint(f);
  u += 0x7fffu + ((u >> 16) & 1u);   // RNE; inputs finite
  return (u16)(u >> 16);
}

// async global->LDS, 16B per lane; LDS dest is wave-uniform base + lane*16
__device__ __forceinline__ void gload16(const u16* g, u16* l) {
  __builtin_amdgcn_global_load_lds(
      (const __attribute__((address_space(1))) unsigned int*)g,
      (__attribute__((address_space(3))) unsigned int*)l, 16, 0, 0);
}

// pack two f32 -> one dword of 2 bf16 (lo = a, hi = b)
__device__ __forceinline__ u32 cvtpk_bf16(float a, float b) {
  u32 r;
  asm volatile("v_cvt_pk_bf16_f32 %0, %1, %2" : "=v"(r) : "v"(a), "v"(b));
  return r;
}

#define BAR()    asm volatile("s_barrier" ::: "memory")
#define WAITV4() asm volatile("s_waitcnt vmcnt(4)" ::: "memory")
#define WAITV2() asm volatile("s_waitcnt vmcnt(2)" ::: "memory")
#define WAITV0() asm volatile("s_waitcnt vmcnt(0)" ::: "memory")

// ---------------------------------------------------------------------------
// LayerNorm: one block per row, fp32 in -> bf16 out
// ---------------------------------------------------------------------------
__global__ __launch_bounds__(256) void ln_kernel(
    const float* __restrict__ x, const float* __restrict__ g,
    const float* __restrict__ be, u16* __restrict__ xn)
{
  int row = blockIdx.x;
  int tid = threadIdx.x;
  const float4* xr = (const float4*)(x + (size_t)row * Dd);
  float4 a = xr[tid];
  float4 b4 = xr[tid + 256];
  float s  = a.x + a.y + a.z + a.w + b4.x + b4.y + b4.z + b4.w;
  float ss = a.x*a.x + a.y*a.y + a.z*a.z + a.w*a.w
           + b4.x*b4.x + b4.y*b4.y + b4.z*b4.z + b4.w*b4.w;
  #pragma unroll
  for (int off = 32; off > 0; off >>= 1) {
    s  += __shfl_down(s, off);
    ss += __shfl_down(ss, off);
  }
  __shared__ float red[8];
  int lane = tid & 63, w = tid >> 6;
  if (lane == 0) { red[w] = s; red[4 + w] = ss; }
  __syncthreads();
  s  = red[0] + red[1] + red[2] + red[3];
  ss = red[4] + red[5] + red[6] + red[7];
  float mu = s * (1.0f / Dd);
  float rs = rsqrtf(ss * (1.0f / Dd) - mu * mu + 1e-5f);

  u16* xo = xn + (size_t)row * Dd;
  const float4* gv4 = (const float4*)g;
  const float4* bv4 = (const float4*)be;
  #pragma unroll
  for (int p = 0; p < 2; ++p) {
    int idx = tid + p * 256;
    float4 xv = (p == 0) ? a : b4;
    float4 gg = gv4[idx], bb = bv4[idx];
    ushort4 pk;
    pk.x = f2bf((xv.x - mu) * rs * gg.x + bb.x);
    pk.y = f2bf((xv.y - mu) * rs * gg.y + bb.y);
    pk.z = f2bf((xv.z - mu) * rs * gg.z + bb.z);
    pk.w = f2bf((xv.w - mu) * rs * gg.w + bb.w);
    *(ushort4*)(xo + idx * 4) = pk;
  }
}

// ---------------------------------------------------------------------------
// Merged weight transpose+cast: all 4 weight matrices in ONE launch.
// Region by flat block id:  [0,4096) Wq -> wqkvT rows 0..2047
//   [4096,5120) Wk -> wqkvT rows 2048..2559
//   [5120,6144) Wv -> wqkvT rows 2560..3071
//   [6144,10240) Wo -> woT.   All sources have K=2048 rows.
// ---------------------------------------------------------------------------
__global__ __launch_bounds__(256) void transpose_all(
    const float* __restrict__ Wq, const float* __restrict__ Wk,
    const float* __restrict__ Wv, const float* __restrict__ Wo,
    u16* __restrict__ wqkvT, u16* __restrict__ woT)
{
  int id = blockIdx.x;
  const float* W; u16* WT; int N, loc;
  if (id < 4096)      { W = Wq; WT = wqkvT;                          N = NQ;  loc = id; }
  else if (id < 5120) { W = Wk; WT = wqkvT + (size_t)NQ * Dd;        N = NKV; loc = id - 4096; }
  else if (id < 6144) { W = Wv; WT = wqkvT + (size_t)(NQ + NKV) * Dd; N = NKV; loc = id - 5120; }
  else                { W = Wo; WT = woT;                            N = NQ;  loc = id - 6144; }
  int nx = N >> 5;
  int n0 = (loc % nx) * 32, k0 = (loc / nx) * 32;

  __shared__ float tile[32][33];
  int tx = threadIdx.x & 31, ty = threadIdx.x >> 5;  // ty 0..7
  #pragma unroll
  for (int i = 0; i < 4; ++i)
    tile[ty + 8 * i][tx] = W[(size_t)(k0 + ty + 8 * i) * N + n0 + tx];
  __syncthreads();
  #pragma unroll
  for (int i = 0; i < 4; ++i)
    WT[(size_t)(n0 + ty + 8 * i) * Dd + k0 + tx] = f2bf(tile[tx][ty + 8 * i]);
}

// ---------------------------------------------------------------------------
// 256x256 8-phase GEMM core (round-7 winner).  512 threads = 8 waves (2Mx4N).
// BK=64, double-buffered LDS 128 KiB, 16B-slot XOR swizzle (slot ^= row&7).
// Stage order per tile t: {A.h0(t+1), A.h1(t+1), B.h0(t+2), B.h1(t+2)};
// boundary vmcnt(4) leaves exactly B(t+2) in flight.
// ---------------------------------------------------------------------------
__device__ __forceinline__ void gemm8_core(
    const u16* __restrict__ A, const u16* __restrict__ BT, int K,
    int brow, int bcol, u16* __restrict__ As, u16* __restrict__ Bs,
    f32x4 (&acc)[8][4])
{
  const int tid  = threadIdx.x;
  const int lane = tid & 63;
  const int wave = tid >> 6;
  const int wr = wave >> 2, wc = wave & 3;
  const int m16 = lane & 15, quad = lane >> 4;
  const int NT = K >> 6;

  const int r0 = tid >> 3;                  // row within half, sweep 0
  const int sg = (tid & 7) ^ (r0 & 7);      // source 16B-slot
  const u16* Asrc = A  + (size_t)(brow + r0) * K + sg * 8;
  const u16* Bsrc = BT + (size_t)(bcol + r0) * K + sg * 8;
  u16* AsW = As + wave * 512;
  u16* BsW = Bs + wave * 512;
  const size_t a64 = (size_t)64 * K;

  const int sl0 = (quad ^ (m16 & 7)) * 8;        // kh=0
  const int sl1 = ((quad | 4) ^ (m16 & 7)) * 8;  // kh=1
  const u16* Afr = As + wr * 8192 + m16 * 64;
  const u16* Bfr = Bs + (wc >> 1) * 8192 + ((wc & 1) * 64 + m16) * 64;

  // ---- prologue: A(0).h01, B(0).h01, then B(1).h01 ----
  #pragma unroll
  for (int h = 0; h < 2; ++h) {
    gload16(Asrc + (size_t)(h * 128) * K, AsW + h * 8192);
    gload16(Asrc + (size_t)(h * 128) * K + a64, AsW + h * 8192 + 4096);
    gload16(Bsrc + (size_t)(h * 128) * K, BsW + h * 8192);
    gload16(Bsrc + (size_t)(h * 128) * K + a64, BsW + h * 8192 + 4096);
  }
  #pragma unroll
  for (int h = 0; h < 2; ++h) {
    gload16(Bsrc + (size_t)(h * 128) * K + 64, BsW + 16384 + h * 8192);
    gload16(Bsrc + (size_t)(h * 128) * K + a64 + 64, BsW + 16384 + h * 8192 + 4096);
  }
  WAITV4();
  BAR();

  for (int t = 0; t < NT; ++t) {
    const int bi = t & 1;
    const u16* Abuf = Afr + bi * 16384;
    const u16* Bbuf = Bfr + bi * 16384;
    s16x8 bfr[4][2];
    #pragma unroll
    for (int ph = 0; ph < 4; ++ph) {
      s16x8 a0k0 = *(const s16x8*)(Abuf + (ph * 2 + 0) * 1024 + sl0);
      s16x8 a0k1 = *(const s16x8*)(Abuf + (ph * 2 + 0) * 1024 + sl1);
      s16x8 a1k0 = *(const s16x8*)(Abuf + (ph * 2 + 1) * 1024 + sl0);
      s16x8 a1k1 = *(const s16x8*)(Abuf + (ph * 2 + 1) * 1024 + sl1);
      if (ph == 0) {
        #pragma unroll
        for (int nj = 0; nj < 4; ++nj) {
          bfr[nj][0] = *(const s16x8*)(Bbuf + nj * 1024 + sl0);
          bfr[nj][1] = *(const s16x8*)(Bbuf + nj * 1024 + sl1);
        }
      }
      if (ph < 2) {
        if (t + 1 < NT) {
          const u16* g = Asrc + (size_t)(ph * 128) * K + (t + 1) * 64;
          u16* l = AsW + (bi ^ 1) * 16384 + ph * 8192;
          gload16(g, l);
          gload16(g + a64, l + 4096);
        }
      } else {
        if (t + 2 < NT) {
          const u16* g = Bsrc + (size_t)((ph - 2) * 128) * K + (t + 2) * 64;
          u16* l = BsW + bi * 16384 + (ph - 2) * 8192;
          gload16(g, l);
          gload16(g + a64, l + 4096);
        }
      }
      BAR();
      __builtin_amdgcn_s_setprio(1);
      #pragma unroll
      for (int nj = 0; nj < 4; ++nj) {
        acc[ph*2+0][nj] = __builtin_amdgcn_mfma_f32_16x16x32_bf16(a0k0, bfr[nj][0], acc[ph*2+0][nj], 0, 0, 0);
        acc[ph*2+0][nj] = __builtin_amdgcn_mfma_f32_16x16x32_bf16(a0k1, bfr[nj][1], acc[ph*2+0][nj], 0, 0, 0);
        acc[ph*2+1][nj] = __builtin_amdgcn_mfma_f32_16x16x32_bf16(a1k0, bfr[nj][0], acc[ph*2+1][nj], 0, 0, 0);
        acc[ph*2+1][nj] = __builtin_amdgcn_mfma_f32_16x16x32_bf16(a1k1, bfr[nj][1], acc[ph*2+1][nj], 0, 0, 0);
      }
      __builtin_amdgcn_s_setprio(0);
      if (ph == 3) {
        if (t + 2 < NT) WAITV4(); else WAITV0();
      }
      BAR();
    }
  }
}

// Fused QKV projection: BT = concat rows [WqT(2048) ; WkT(512) ; WvT(512)].
// V region written DIRECTLY TRANSPOSED into vT[(b*512+col)][t] -> no
// transpose_v pass.  Q pre-scaled to base-2 domain.
__global__ __launch_bounds__(512) void gemm8_qkv(
    const u16* __restrict__ A, const u16* __restrict__ BT,
    const float* __restrict__ bq, const float* __restrict__ bk,
    const float* __restrict__ bv,
    u16* __restrict__ qb, u16* __restrict__ kb, u16* __restrict__ vT)
{
  __shared__ u16 As[32768];
  __shared__ u16 Bs[32768];
  int nbx = 12;
  int id  = blockIdx.y * nbx + blockIdx.x;
  int nwg = 192;
  int swz = (id & 7) * (nwg >> 3) + (id >> 3);
  int bx = swz % nbx, by = swz / nbx;

  f32x4 acc[8][4] = {};
  gemm8_core(A, BT, Dd, by * 256, bx * 256, As, Bs, acc);

  int lane = threadIdx.x & 63, wave = threadIdx.x >> 6;
  int wr = wave >> 2, wc = wave & 3;
  int m16 = lane & 15, quad = lane >> 4;
  int wcol = (wc >> 1) * 128 + (wc & 1) * 64;

  if (bx < 8) {           // ---- Q: rowmajor bf16, pre-scaled ----
    int colb = bx * 256 + wcol;
    #pragma unroll
    for (int nj = 0; nj < 4; ++nj) {
      int col = colb + nj * 16 + m16;
      float bc = bq[col];
      #pragma unroll
      for (int mi = 0; mi < 8; ++mi)
        #pragma unroll
        for (int rr = 0; rr < 4; ++rr) {
          int row = by * 256 + wr * 128 + mi * 16 + quad * 4 + rr;
          qb[(size_t)row * NQ + col] = f2bf((acc[mi][nj][rr] + bc) * (0.125f * LOG2E));
        }
    }
  } else if (bx < 10) {   // ---- K: rowmajor bf16 ----
    int colb = (bx - 8) * 256 + wcol;
    #pragma unroll
    for (int nj = 0; nj < 4; ++nj) {
      int col = colb + nj * 16 + m16;
      float bc = bk[col];
      #pragma unroll
      for (int mi = 0; mi < 8; ++mi)
        #pragma unroll
        for (int rr = 0; rr < 4; ++rr) {
          int row = by * 256 + wr * 128 + mi * 16 + quad * 4 + rr;
          kb[(size_t)row * NKV + col] = f2bf(acc[mi][nj][rr] + bc);
        }
    }
  } else {                // ---- V: transposed write vT[(b*512+col)][t] ----
    int colb = (bx - 10) * 256 + wcol;
    #pragma unroll
    for (int nj = 0; nj < 4; ++nj) {
      int col = colb + nj * 16 + m16;
      float bc = bv[col];
      #pragma unroll
      for (int mi = 0; mi < 8; ++mi) {
        int row = by * 256 + wr * 128 + mi * 16 + quad * 4;   // 4 consecutive t
        int b = row >> 11, t = row & 2047;
        ushort4 pk;
        pk.x = f2bf(acc[mi][nj][0] + bc);
        pk.y = f2bf(acc[mi][nj][1] + bc);
        pk.z = f2bf(acc[mi][nj][2] + bc);
        pk.w = f2bf(acc[mi][nj][3] + bc);
        *(ushort4*)(vT + ((size_t)(b * NKV + col)) * Ss + t) = pk;
      }
    }
  }
}

// ---------------------------------------------------------------------------
// Wo projection, 256M x 128N 8-phase variant: grid 16x16 = 256 blocks = 1/CU.
// ---------------------------------------------------------------------------
__global__ __launch_bounds__(512) void gemm8_wo(
    const u16* __restrict__ A, const u16* __restrict__ BT,
    const float* __restrict__ bias, float* __restrict__ C, int N, int K)
{
  __shared__ u16 As[32768];   // 64 KB
  __shared__ u16 Bs[16384];   // 32 KB
  int nbx = N >> 7;                        // 16
  int id  = blockIdx.y * nbx + blockIdx.x;
  int nwg = gridDim.x * gridDim.y;         // 256
  int swz = (id & 7) * (nwg >> 3) + (id >> 3);
  int bx = swz % nbx, by = swz / nbx;

  const int tid  = threadIdx.x;
  const int lane = tid & 63;
  const int wave = tid >> 6;
  const int wr = wave >> 2, wc = wave & 3; // wr: M-half, wc: 32-col strip
  const int m16 = lane & 15, quad = lane >> 4;
  const int NT = K >> 6;

  const int r0 = tid >> 3;
  const int sg = (tid & 7) ^ (r0 & 7);
  const u16* Asrc = A  + (size_t)(by * 256 + r0) * K + sg * 8;
  const u16* Bsrc = BT + (size_t)(bx * 128 + r0) * K + sg * 8;
  u16* AsW = As + wave * 512;
  u16* BsW = Bs + wave * 512;
  const size_t a64 = (size_t)64 * K;

  const int sl0 = (quad ^ (m16 & 7)) * 8;
  const int sl1 = ((quad | 4) ^ (m16 & 7)) * 8;
  const u16* Afr = As + wr * 8192 + m16 * 64;
  const u16* Bfr = Bs + (wc * 32 + m16) * 64;

  f32x4 acc[8][2] = {};

  // prologue: A(0).h0 [2], A(0).h1 [2], B(0) [2], B(1) [2]
  #pragma unroll
  for (int h = 0; h < 2; ++h) {
    gload16(Asrc + (size_t)(h * 128) * K, AsW + h * 8192);
    gload16(Asrc + (size_t)(h * 128) * K + a64, AsW + h * 8192 + 4096);
  }
  gload16(Bsrc, BsW);
  gload16(Bsrc + a64, BsW + 4096);
  gload16(Bsrc + 64, BsW + 8192);
  gload16(Bsrc + a64 + 64, BsW + 8192 + 4096);
  WAITV2();
  BAR();

  for (int t = 0; t < NT; ++t) {
    const int bi = t & 1;
    const u16* Abuf = Afr + bi * 16384;
    const u16* Bbuf = Bfr + bi * 8192;
    s16x8 bfr[2][2];
    #pragma unroll
    for (int ph = 0; ph < 4; ++ph) {
      s16x8 a0k0 = *(const s16x8*)(Abuf + (ph * 2 + 0) * 1024 + sl0);
      s16x8 a0k1 = *(const s16x8*)(Abuf + (ph * 2 + 0) * 1024 + sl1);
      s16x8 a1k0 = *(const s16x8*)(Abuf + (ph * 2 + 1) * 1024 + sl0);
      s16x8 a1k1 = *(const s16x8*)(Abuf + (ph * 2 + 1) * 1024 + sl1);
      if (ph == 0) {
        #pragma unroll
        for (int nj = 0; nj < 2; ++nj) {
          bfr[nj][0] = *(const s16x8*)(Bbuf + nj * 1024 + sl0);
          bfr[nj][1] = *(const s16x8*)(Bbuf + nj * 1024 + sl1);
        }
      }
      if (ph < 2) {
        if (t + 1 < NT) {
          const u16* g = Asrc + (size_t)(ph * 128) * K + (t + 1) * 64;
          u16* l = AsW + (bi ^ 1) * 16384 + ph * 8192;
          gload16(g, l);
          gload16(g + a64, l + 4096);
        }
      } else if (ph == 2) {
        if (t + 2 < NT) {
          const u16* g = Bsrc + (size_t)(t + 2) * 64;
          u16* l = BsW + bi * 8192;
          gload16(g, l);
          gload16(g + a64, l + 4096);
        }
      }
      BAR();
      __builtin_amdgcn_s_setprio(1);
      #pragma unroll
      for (int nj = 0; nj < 2; ++nj) {
        acc[ph*2+0][nj] = __builtin_amdgcn_mfma_f32_16x16x32_bf16(a0k0, bfr[nj][0], acc[ph*2+0][nj], 0, 0, 0);
        acc[ph*2+0][nj] = __builtin_amdgcn_mfma_f32_16x16x32_bf16(a0k1, bfr[nj][1], acc[ph*2+0][nj], 0, 0, 0);
        acc[ph*2+1][nj] = __builtin_amdgcn_mfma_f32_16x16x32_bf16(a1k0, bfr[nj][0], acc[ph*2+1][nj], 0, 0, 0);
        acc[ph*2+1][nj] = __builtin_amdgcn_mfma_f32_16x16x32_bf16(a1k1, bfr[nj][1], acc[ph*2+1][nj], 0, 0, 0);
      }
      __builtin_amdgcn_s_setprio(0);
      if (ph == 3) {
        if (t + 2 < NT) WAITV2(); else WAITV0();
      }
      BAR();
    }
  }

  int colb = bx * 128 + wc * 32;
  #pragma unroll
  for (int nj = 0; nj < 2; ++nj) {
    int col = colb + nj * 16 + m16;
    float bc = bias[col];
    #pragma unroll
    for (int mi = 0; mi < 8; ++mi)
      #pragma unroll
      for (int rr = 0; rr < 4; ++rr) {
        int row = by * 256 + wr * 128 + mi * 16 + quad * 4 + rr;
        C[(size_t)row * N + col] = acc[mi][nj][rr] + bc;
      }
  }
}

// ---------------------------------------------------------------------------
// Pass A: per-column softmax stats over the QUERY axis (base-2 domain).
// Writes cst NEGATED: cst[T] = -(m2 + log2 l).
// ---------------------------------------------------------------------------
__global__ __launch_bounds__(256) void pass_a_mfma(
    const u16* __restrict__ qb, const u16* __restrict__ kb,
    float* __restrict__ cst)
{
  __shared__ u16 Qs[2][64 * 64];   // 16 KB
  int combo = blockIdx.x;
  int qk = combo & 3, bh = combo >> 2;
  int b = bh >> 3, h = bh & 7;
  int g = blockIdx.y;                     // 0..15, longest first
  int tid = threadIdx.x;
  int lane = tid & 63, wave = tid >> 6;
  int m16 = lane & 15, quad = lane >> 4;
  int T0w = g * 128 + wave * 32;          // wave's 32 T-columns

  const u16* kbase = kb + (size_t)b * Ss * NKV + h * HD;
  const u16* qbase = qb + (size_t)b * Ss * NQ + (h * QPK + qk) * HD;

  s16x8 kf[2][2];   // B-operand frags (n=T), loaded once
  #pragma unroll
  for (int jg = 0; jg < 2; ++jg)
    #pragma unroll
    for (int dc = 0; dc < 2; ++dc)
      kf[jg][dc] = *(const s16x8*)(kbase + (size_t)(T0w + jg * 16 + m16) * NKV + dc * 32 + quad * 8);

  float ms[2] = {-1e30f, -1e30f};
  float ls[2] = {0.f, 0.f};
  int srow  = (wave << 3) + (lane >> 3);
  int slot0 = (lane & 7) ^ (lane >> 3);
  int sl0 = quad ^ (m16 & 7);
  int sl1 = (quad | 4) ^ (m16 & 7);
  int tDiag = T0w & ~63;

  // prologue: stage tile t0 = g*128 into Qs[0]
  {
    u16* QsW = &Qs[0][(wave * 8) * 64];
    int t0 = g * 128;
    gload16(qbase + (size_t)(t0 + srow) * NQ + slot0 * 8, QsW);
    gload16(qbase + (size_t)(t0 + srow + 32) * NQ + slot0 * 8, QsW + 32 * 64);
  }

  for (int t0 = g * 128; t0 < Ss; t0 += 64) {
    int cur = (t0 >> 6) & 1;
    bool nxt = (t0 + 64 < Ss);
    if (nxt) {
      u16* QsW = &Qs[cur ^ 1][(wave * 8) * 64];
      gload16(qbase + (size_t)(t0 + 64 + srow) * NQ + slot0 * 8, QsW);
      gload16(qbase + (size_t)(t0 + 64 + srow + 32) * NQ + slot0 * 8, QsW + 32 * 64);
      WAITV2();
    } else {
      WAITV0();
    }
    BAR();
    if (t0 + 63 < T0w) { BAR(); continue; }   // wave inactive; barriers matched

    const u16* Qc = &Qs[cur][0];
    s16x8 af[4][2];
    #pragma unroll
    for (int i = 0; i < 4; ++i) {
      af[i][0] = *(const s16x8*)(Qc + (i * 16 + m16) * 64 + sl0 * 8);
      af[i][1] = *(const s16x8*)(Qc + (i * 16 + m16) * 64 + sl1 * 8);
    }
    f32x4 acc[4][2];
    #pragma unroll
    for (int i = 0; i < 4; ++i)
      #pragma unroll
      for (int jg = 0; jg < 2; ++jg) {
        f32x4 z = {};
        z = __builtin_amdgcn_mfma_f32_16x16x32_bf16(af[i][0], kf[jg][0], z, 0, 0, 0);
        acc[i][jg] = __builtin_amdgcn_mfma_f32_16x16x32_bf16(af[i][1], kf[jg][1], z, 0, 0, 0);
      }
    if (t0 == tDiag) {   // diagonal block: mask t < T with very-low sentinel
      #pragma unroll
      for (int i = 0; i < 4; ++i)
        #pragma unroll
        for (int jg = 0; jg < 2; ++jg) {
          int tg = t0 + i * 16 + quad * 4;
          int Tg = T0w + jg * 16 + m16;
          #pragma unroll
          for (int r = 0; r < 4; ++r)
            if (tg + r < Tg) acc[i][jg][r] = -3e38f;
        }
    }
    #pragma unroll
    for (int jg = 0; jg < 2; ++jg) {
      float bm = -3e38f;
      #pragma unroll
      for (int i = 0; i < 4; ++i)
        #pragma unroll
        for (int r = 0; r < 4; ++r) bm = fmaxf(bm, acc[i][jg][r]);
      float mn = fmaxf(ms[jg], bm);
      float se = 0.f;
      #pragma unroll
      for (int i = 0; i < 4; ++i)
        #pragma unroll
        for (int r = 0; r < 4; ++r) se += exp2f(acc[i][jg][r] - mn);
      ls[jg] = ls[jg] * exp2f(ms[jg] - mn) + se;
      ms[jg] = mn;
    }
    BAR();
  }
  // cross-quad merge (cols live on m16; quads hold disjoint t-subsets)
  #pragma unroll
  for (int jg = 0; jg < 2; ++jg) {
    float m = ms[jg], l = ls[jg];
    #pragma unroll
    for (int off = 16; off <= 32; off <<= 1) {
      float mo = __shfl_xor(m, off);
      float lo = __shfl_xor(l, off);
      float mn = fmaxf(m, mo);
      l = l * exp2f(m - mn) + lo * exp2f(mo - mn);
      m = mn;
    }
    if (quad == 0)
      cst[(size_t)(bh * QPK + qk) * Ss + T0w + jg * 16 + m16] = -(m + __log2f(l));
  }
}

// ---------------------------------------------------------------------------
// Pass B: out[t,:] = sum_{T<=t} exp2(s2(t,T)+negc[T]) * v[T,:]
// K AND V double-buffered in LDS (counted vmcnt(4)); negc folded into the
// QK MFMA accumulator init.  P never touches LDS: cvt_pk + permlane swaps.
// ---------------------------------------------------------------------------
__global__ __launch_bounds__(256) void pass_b_mfma(
    const u16* __restrict__ qb, const u16* __restrict__ kb,
    const u16* __restrict__ vT, const float* __restrict__ cst,
    u16* __restrict__ attn)
{
  __shared__ u16 Ks[2][64 * 64];   // 16 KB
  __shared__ u16 Vs[2][64 * 64];   // 16 KB
  int combo = blockIdx.x;
  int qk = combo & 3, bh = combo >> 2;
  int b = bh >> 3, h = bh & 7;
  int g = 31 - blockIdx.y;                // longest first
  int tid = threadIdx.x;
  int lane = tid & 63, wave = tid >> 6;
  int m16 = lane & 15, quad = lane >> 4;
  int trow = g * 64 + wave * 16;          // wave's 16 t-rows

  const u16* qbase = qb + (size_t)b * Ss * NQ + (h * QPK + qk) * HD;
  const u16* kbase = kb + (size_t)b * Ss * NKV + h * HD;
  const u16* vbase = vT + (size_t)(bh * 64) * Ss;
  const float* cbase = cst + (size_t)(bh * QPK + qk) * Ss;

  s16x8 qf[2];   // B-operand (n=t) frags for this wave's rows
  #pragma unroll
  for (int dc = 0; dc < 2; ++dc)
    qf[dc] = *(const s16x8*)(qbase + (size_t)(trow + m16) * NQ + dc * 32 + quad * 8);

  f32x4 oacc[4] = {};   // C-layout: row t = quad*4+r, col d = dj*16+m16
  int srow  = (wave << 3) + (lane >> 3);
  int slot0 = (lane & 7) ^ (lane >> 3);
  int sl0 = quad ^ (m16 & 7);
  int sl1 = (quad | 4) ^ (m16 & 7);
  int Tend = g * 64;

  // prologue: stage K+V tile 0 into buf 0
  {
    u16* KsW = &Ks[0][(wave * 8) * 64];
    u16* VsW = &Vs[0][(wave * 8) * 64];
    gload16(kbase + (size_t)srow * NKV + slot0 * 8, KsW);
    gload16(kbase + (size_t)(srow + 32) * NKV + slot0 * 8, KsW + 32 * 64);
    gload16(vbase + (size_t)srow * Ss + slot0 * 8, VsW);
    gload16(vbase + (size_t)(srow + 32) * Ss + slot0 * 8, VsW + 32 * 64);
  }

  for (int T0 = 0; T0 <= Tend; T0 += 64) {
    int cur = (T0 >> 6) & 1;
    bool nxt = (T0 + 64 <= Tend);
    // negc loads for THIS tile -- issued before next-tile stage (ordering
    // matters: compiler's wait-for-cc then leaves the stage loads in flight)
    float4 cc[4];
    #pragma unroll
    for (int i = 0; i < 4; ++i)
      cc[i] = *(const float4*)(cbase + T0 + i * 16 + quad * 4);
    __builtin_amdgcn_sched_barrier(0);
    if (nxt) {
      u16* KsW = &Ks[cur ^ 1][(wave * 8) * 64];
      u16* VsW = &Vs[cur ^ 1][(wave * 8) * 64];
      gload16(kbase + (size_t)(T0 + 64 + srow) * NKV + slot0 * 8, KsW);
      gload16(kbase + (size_t)(T0 + 64 + srow + 32) * NKV + slot0 * 8, KsW + 32 * 64);
      gload16(vbase + (size_t)srow * Ss + T0 + 64 + slot0 * 8, VsW);
      gload16(vbase + (size_t)(srow + 32) * Ss + T0 + 64 + slot0 * 8, VsW + 32 * 64);
      WAITV4();   // drains prev stage + cc; leaves the 4 new stage loads
    } else {
      WAITV0();
    }
    BAR();
    bool diag = (T0 == Tend);
    const u16* Kc = &Ks[cur][0];
    const u16* Vc = &Vs[cur][0];
    // tc = T-chunk of 32 (PV k-dim); i = score T-row-block of 16
    #pragma unroll
    for (int tc = 0; tc < 2; ++tc) {
      u32 A[2], Bw[2];
      #pragma unroll
      for (int ii = 0; ii < 2; ++ii) {
        int i = tc * 2 + ii;
        s16x8 k0 = *(const s16x8*)(Kc + (i * 16 + m16) * 64 + sl0 * 8);
        s16x8 k1 = *(const s16x8*)(Kc + (i * 16 + m16) * 64 + sl1 * 8);
        float4 c4 = cc[i];
        f32x4 z = {c4.x, c4.y, c4.z, c4.w};   // acc-init = -c (pre-negated)
        z = __builtin_amdgcn_mfma_f32_16x16x32_bf16(k0, qf[0], z, 0, 0, 0);
        z = __builtin_amdgcn_mfma_f32_16x16x32_bf16(k1, qf[1], z, 0, 0, 0);
        float w0 = exp2f(z[0]);
        float w1 = exp2f(z[1]);
        float w2 = exp2f(z[2]);
        float w3 = exp2f(z[3]);
        if (diag) {
          int t  = trow + m16;
          int Tg = T0 + i * 16 + quad * 4;
          if (Tg + 0 > t) w0 = 0.f;
          if (Tg + 1 > t) w1 = 0.f;
          if (Tg + 2 > t) w2 = 0.f;
          if (Tg + 3 > t) w3 = 0.f;
        }
        A[ii]  = cvtpk_bf16(w0, w1);
        Bw[ii] = cvtpk_bf16(w2, w3);
      }
      // cross-quad redistribution: quads {0,1}->dest {0,2}, {2,3}->dest {1,3}
      asm volatile("v_permlane32_swap_b32 %0, %1" : "+v"(A[0]),  "+v"(A[1]));
      asm volatile("v_permlane16_swap_b32 %0, %1" : "+v"(A[0]),  "+v"(A[1]));
      asm volatile("v_permlane32_swap_b32 %0, %1" : "+v"(Bw[0]), "+v"(Bw[1]));
      asm volatile("v_permlane16_swap_b32 %0, %1" : "+v"(Bw[0]), "+v"(Bw[1]));
      union { uint4 u; s16x8 v; } pu;
      pu.u.x = A[0]; pu.u.y = Bw[0]; pu.u.z = A[1]; pu.u.w = Bw[1];
      s16x8 pa = pu.v;   // A-operand: P[t=m16][T = T0 + tc*32 + quad*8 + j]
      #pragma unroll
      for (int dj = 0; dj < 4; ++dj) {
        int vsl = (quad | (tc << 2)) ^ (m16 & 7);
        s16x8 vf = *(const s16x8*)(Vc + (dj * 16 + m16) * 64 + vsl * 8);
        oacc[dj] = __builtin_amdgcn_mfma_f32_16x16x32_bf16(pa, vf, oacc[dj], 0, 0, 0);
      }
    }
    BAR();
  }
  // ---- epilogue: attn (b, t, (h*QPK+qk)*64 + d) bf16 ----
  u16* abase = attn + (size_t)b * Ss * NQ + (h * QPK + qk) * HD;
  #pragma unroll
  for (int dj = 0; dj < 4; ++dj)
    #pragma unroll
    for (int r = 0; r < 4; ++r)
      abase[(size_t)(trow + quad * 4 + r) * NQ + dj * 16 + m16] = f2bf(oacc[dj][r]);
}

// ---------------------------------------------------------------------------
extern "C" void kernel_launch(void* const* d_in, const int* in_sizes, int n_in,
                              void* d_out, int out_size, void* d_ws, size_t ws_size,
                              hipStream_t stream)
{
  (void)in_sizes; (void)n_in; (void)out_size; (void)ws_size;
  const float* x   = (const float*)d_in[0];
  const float* lng = (const float*)d_in[1];
  const float* lnb = (const float*)d_in[2];
  const float* Wq  = (const float*)d_in[3];
  const float* bq  = (const float*)d_in[4];
  const float* Wk  = (const float*)d_in[5];
  const float* bk  = (const float*)d_in[6];
  const float* Wv  = (const float*)d_in[7];
  const float* bv  = (const float*)d_in[8];
  const float* Wo  = (const float*)d_in[9];
  const float* bo  = (const float*)d_in[10];
  float* out = (float*)d_out;

  char* ws = (char*)d_ws;
  size_t off = 0;
  auto take = [&](size_t bytes) -> char* {
    char* p = ws + off;
    off += (bytes + 255) & ~(size_t)255;
    return p;
  };
  u16*    xnb   = (u16*)take((size_t)MR * Dd * 2);             // 16 MB
  u16*    wqkvT = (u16*)take((size_t)(NQ + 2 * NKV) * Dd * 2); // 12 MB (Q;K;V rows)
  u16*    woT   = (u16*)take((size_t)Dd * NQ * 2);             // 8 MB
  u16*    qbB   = (u16*)take((size_t)MR * NQ * 2);             // 16 MB
  u16*    kbB   = (u16*)take((size_t)MR * NKV * 2);            // 4 MB
  u16*    vTb   = (u16*)take((size_t)MR * NKV * 2);            // 4 MB (transposed)
  float*  cst   = (float*)take((size_t)Bb * HKV * QPK * Ss * 4); // 0.5 MB
  u16*    attnb = (u16*)take((size_t)MR * NQ * 2);             // 16 MB

  ln_kernel<<<MR, 256, 0, stream>>>(x, lng, lnb, xnb);
  // all 4 weight transposes in one launch
  transpose_all<<<10240, 256, 0, stream>>>(Wq, Wk, Wv, Wo, wqkvT, woT);

  // fused Q/K/V projection (q pre-scaled; V written directly transposed)
  gemm8_qkv<<<dim3(12, 16), 512, 0, stream>>>(xnb, wqkvT, bq, bk, bv, qbB, kbB, vTb);

  pass_a_mfma<<<dim3(64, 16), 256, 0, stream>>>(qbB, kbB, cst);
  pass_b_mfma<<<dim3(64, 32), 256, 0, stream>>>(qbB, kbB, vTb, cst, attnb);

  gemm8_wo<<<dim3(16, 16), 512, 0, stream>>>(attnb, woT, bo, out, Dd, NQ);
}

// Round 11
// 364.315 us; speedup vs baseline: 1.0838x; 1.0485x over previous
//
#include <hip/hip_runtime.h>

// Problem constants (fixed by the reference)
#define Bb  2
#define Ss  2048
#define Dd  2048
#define HKV 8
#define QPK 4
#define HD  64
#define MR  (Bb * Ss)   // 4096 token rows
#define NQ  2048        // HQ*HD
#define NKV 512         // HKV*HD

#define LOG2E 1.4426950408889634f

typedef unsigned short u16;
typedef unsigned int u32;
typedef __attribute__((ext_vector_type(8))) short s16x8;   // 8 x bf16 (4 VGPRs)
typedef __attribute__((ext_vector_type(4))) float f32x4;   // MFMA accumulator

__device__ __forceinline__ u16 f2bf(float f) {
  unsigned u = __float_as_uint(f);
  u += 0x7fffu + ((u >> 16) & 1u);   // RNE; inputs finite
  return (u16)(u >> 16);
}

// async global->LDS, 16B per lane; LDS dest is wave-uniform base + lane*16
__device__ __forceinline__ void gload16(const u16* g, u16* l) {
  __builtin_amdgcn_global_load_lds(
      (const __attribute__((address_space(1))) unsigned int*)g,
      (__attribute__((address_space(3))) unsigned int*)l, 16, 0, 0);
}

// pack two f32 -> one dword of 2 bf16 (lo = a, hi = b)
__device__ __forceinline__ u32 cvtpk_bf16(float a, float b) {
  u32 r;
  asm volatile("v_cvt_pk_bf16_f32 %0, %1, %2" : "=v"(r) : "v"(a), "v"(b));
  return r;
}

#define BAR()    asm volatile("s_barrier" ::: "memory")
#define WAITV8() asm volatile("s_waitcnt vmcnt(8)" ::: "memory")
#define WAITV6() asm volatile("s_waitcnt vmcnt(6)" ::: "memory")
#define WAITV4() asm volatile("s_waitcnt vmcnt(4)" ::: "memory")
#define WAITV2() asm volatile("s_waitcnt vmcnt(2)" ::: "memory")
#define WAITV0() asm volatile("s_waitcnt vmcnt(0)" ::: "memory")
#define LGKM0()  asm volatile("s_waitcnt lgkmcnt(0)" ::: "memory")

// ---------------------------------------------------------------------------
// LayerNorm: one block per row, fp32 in -> bf16 out
// ---------------------------------------------------------------------------
__global__ __launch_bounds__(256) void ln_kernel(
    const float* __restrict__ x, const float* __restrict__ g,
    const float* __restrict__ be, u16* __restrict__ xn)
{
  int row = blockIdx.x;
  int tid = threadIdx.x;
  const float4* xr = (const float4*)(x + (size_t)row * Dd);
  float4 a = xr[tid];
  float4 b4 = xr[tid + 256];
  float s  = a.x + a.y + a.z + a.w + b4.x + b4.y + b4.z + b4.w;
  float ss = a.x*a.x + a.y*a.y + a.z*a.z + a.w*a.w
           + b4.x*b4.x + b4.y*b4.y + b4.z*b4.z + b4.w*b4.w;
  #pragma unroll
  for (int off = 32; off > 0; off >>= 1) {
    s  += __shfl_down(s, off);
    ss += __shfl_down(ss, off);
  }
  __shared__ float red[8];
  int lane = tid & 63, w = tid >> 6;
  if (lane == 0) { red[w] = s; red[4 + w] = ss; }
  __syncthreads();
  s  = red[0] + red[1] + red[2] + red[3];
  ss = red[4] + red[5] + red[6] + red[7];
  float mu = s * (1.0f / Dd);
  float rs = rsqrtf(ss * (1.0f / Dd) - mu * mu + 1e-5f);

  u16* xo = xn + (size_t)row * Dd;
  const float4* gv4 = (const float4*)g;
  const float4* bv4 = (const float4*)be;
  #pragma unroll
  for (int p = 0; p < 2; ++p) {
    int idx = tid + p * 256;
    float4 xv = (p == 0) ? a : b4;
    float4 gg = gv4[idx], bb = bv4[idx];
    ushort4 pk;
    pk.x = f2bf((xv.x - mu) * rs * gg.x + bb.x);
    pk.y = f2bf((xv.y - mu) * rs * gg.y + bb.y);
    pk.z = f2bf((xv.z - mu) * rs * gg.z + bb.z);
    pk.w = f2bf((xv.w - mu) * rs * gg.w + bb.w);
    *(ushort4*)(xo + idx * 4) = pk;
  }
}

// ---------------------------------------------------------------------------
// Merged weight transpose+cast: all 4 weight matrices in ONE launch.
// ---------------------------------------------------------------------------
__global__ __launch_bounds__(256) void transpose_all(
    const float* __restrict__ Wq, const float* __restrict__ Wk,
    const float* __restrict__ Wv, const float* __restrict__ Wo,
    u16* __restrict__ wqkvT, u16* __restrict__ woT)
{
  int id = blockIdx.x;
  const float* W; u16* WT; int N, loc;
  if (id < 4096)      { W = Wq; WT = wqkvT;                          N = NQ;  loc = id; }
  else if (id < 5120) { W = Wk; WT = wqkvT + (size_t)NQ * Dd;        N = NKV; loc = id - 4096; }
  else if (id < 6144) { W = Wv; WT = wqkvT + (size_t)(NQ + NKV) * Dd; N = NKV; loc = id - 5120; }
  else                { W = Wo; WT = woT;                            N = NQ;  loc = id - 6144; }
  int nx = N >> 5;
  int n0 = (loc % nx) * 32, k0 = (loc / nx) * 32;

  __shared__ float tile[32][33];
  int tx = threadIdx.x & 31, ty = threadIdx.x >> 5;  // ty 0..7
  #pragma unroll
  for (int i = 0; i < 4; ++i)
    tile[ty + 8 * i][tx] = W[(size_t)(k0 + ty + 8 * i) * N + n0 + tx];
  __syncthreads();
  #pragma unroll
  for (int i = 0; i < 4; ++i)
    WT[(size_t)(n0 + ty + 8 * i) * Dd + k0 + tx] = f2bf(tile[tx][ty + 8 * i]);
}

// ---------------------------------------------------------------------------
// 256x256 8-phase GEMM core, deepened A-prefetch:
// ph0 reads ALL 16 A-fragments + 8 B-fragments into registers (frees both
// LDS buffers), then ph1-3 stage the ENTIRE tile t+2 (A 4 loads, B 4 loads)
// into the just-freed parity buffers.  Boundary vmcnt(8) leaves exactly
// tile t+2's 8 loads in flight and drains t+1 -- both operands now get
// 4-7 phases of HBM-latency slack (was 3 for A).  Explicit lgkmcnt(0)
// before ph0's closing barrier makes the ph1 overwrite race-free.
// ---------------------------------------------------------------------------
__device__ __forceinline__ void gemm8_core(
    const u16* __restrict__ A, const u16* __restrict__ BT, int K,
    int brow, int bcol, u16* __restrict__ As, u16* __restrict__ Bs,
    f32x4 (&acc)[8][4])
{
  const int tid  = threadIdx.x;
  const int lane = tid & 63;
  const int wave = tid >> 6;
  const int wr = wave >> 2, wc = wave & 3;
  const int m16 = lane & 15, quad = lane >> 4;
  const int NT = K >> 6;

  const int r0 = tid >> 3;                  // row within half, sweep 0
  const int sg = (tid & 7) ^ (r0 & 7);      // source 16B-slot
  const u16* Asrc = A  + (size_t)(brow + r0) * K + sg * 8;
  const u16* Bsrc = BT + (size_t)(bcol + r0) * K + sg * 8;
  u16* AsW = As + wave * 512;
  u16* BsW = Bs + wave * 512;
  const size_t a64  = (size_t)64 * K;
  const size_t a128 = (size_t)128 * K;

  const int sl0 = (quad ^ (m16 & 7)) * 8;        // kh=0
  const int sl1 = ((quad | 4) ^ (m16 & 7)) * 8;  // kh=1
  const u16* Afr = As + wr * 8192 + m16 * 64;
  const u16* Bfr = Bs + (wc >> 1) * 8192 + ((wc & 1) * 64 + m16) * 64;

  // ---- prologue: full tiles t0 -> buf0, t1 -> buf1 (8 loads each) ----
  #pragma unroll
  for (int tt = 0; tt < 2; ++tt) {
    #pragma unroll
    for (int h = 0; h < 2; ++h) {
      gload16(Asrc + h * a128 + tt * 64,       AsW + tt * 16384 + h * 8192);
      gload16(Asrc + h * a128 + a64 + tt * 64, AsW + tt * 16384 + h * 8192 + 4096);
      gload16(Bsrc + h * a128 + tt * 64,       BsW + tt * 16384 + h * 8192);
      gload16(Bsrc + h * a128 + a64 + tt * 64, BsW + tt * 16384 + h * 8192 + 4096);
    }
  }
  WAITV8();   // t0's 8 landed; t1's 8 in flight
  BAR();

  for (int t = 0; t < NT; ++t) {
    const int bi = t & 1;
    const u16* Abuf = Afr + bi * 16384;
    const u16* Bbuf = Bfr + bi * 16384;
    const bool st = (t + 2 < NT);
    const u16* Ag2 = Asrc + (size_t)(t + 2) * 64;
    const u16* Bg2 = Bsrc + (size_t)(t + 2) * 64;
    u16* AsN = AsW + bi * 16384;   // tile t+2 has parity bi
    u16* BsN = BsW + bi * 16384;

    // ph0: read ALL fragments for this K-tile into registers
    s16x8 af[8][2], bfr[4][2];
    #pragma unroll
    for (int mi = 0; mi < 8; ++mi) {
      af[mi][0] = *(const s16x8*)(Abuf + mi * 1024 + sl0);
      af[mi][1] = *(const s16x8*)(Abuf + mi * 1024 + sl1);
    }
    #pragma unroll
    for (int nj = 0; nj < 4; ++nj) {
      bfr[nj][0] = *(const s16x8*)(Bbuf + nj * 1024 + sl0);
      bfr[nj][1] = *(const s16x8*)(Bbuf + nj * 1024 + sl1);
    }
    #pragma unroll
    for (int ph = 0; ph < 4; ++ph) {
      if (st) {
        if (ph == 1) {            // A(t+2).h0
          gload16(Ag2,       AsN);
          gload16(Ag2 + a64, AsN + 4096);
        } else if (ph == 2) {     // A(t+2).h1 + B(t+2).h0
          gload16(Ag2 + a128,       AsN + 8192);
          gload16(Ag2 + a128 + a64, AsN + 8192 + 4096);
          gload16(Bg2,       BsN);
          gload16(Bg2 + a64, BsN + 4096);
        } else if (ph == 3) {     // B(t+2).h1
          gload16(Bg2 + a128,       BsN + 8192);
          gload16(Bg2 + a128 + a64, BsN + 8192 + 4096);
        }
      }
      BAR();
      __builtin_amdgcn_s_setprio(1);
      #pragma unroll
      for (int nj = 0; nj < 4; ++nj) {
        acc[ph*2+0][nj] = __builtin_amdgcn_mfma_f32_16x16x32_bf16(af[ph*2+0][0], bfr[nj][0], acc[ph*2+0][nj], 0, 0, 0);
        acc[ph*2+0][nj] = __builtin_amdgcn_mfma_f32_16x16x32_bf16(af[ph*2+0][1], bfr[nj][1], acc[ph*2+0][nj], 0, 0, 0);
        acc[ph*2+1][nj] = __builtin_amdgcn_mfma_f32_16x16x32_bf16(af[ph*2+1][0], bfr[nj][0], acc[ph*2+1][nj], 0, 0, 0);
        acc[ph*2+1][nj] = __builtin_amdgcn_mfma_f32_16x16x32_bf16(af[ph*2+1][1], bfr[nj][1], acc[ph*2+1][nj], 0, 0, 0);
      }
      __builtin_amdgcn_s_setprio(0);
      if (ph == 0) LGKM0();       // all 24 ds_reads drained before buffers are overwritten
      if (ph == 3) {
        if (st) WAITV8(); else WAITV0();
      }
      BAR();
    }
  }
}

// Fused QKV projection: BT = concat rows [WqT(2048) ; WkT(512) ; WvT(512)].
// V region written DIRECTLY TRANSPOSED into vT[(b*512+col)][t].
__global__ __launch_bounds__(512) void gemm8_qkv(
    const u16* __restrict__ A, const u16* __restrict__ BT,
    const float* __restrict__ bq, const float* __restrict__ bk,
    const float* __restrict__ bv,
    u16* __restrict__ qb, u16* __restrict__ kb, u16* __restrict__ vT)
{
  __shared__ u16 As[32768];
  __shared__ u16 Bs[32768];
  int nbx = 12;
  int id  = blockIdx.y * nbx + blockIdx.x;
  int nwg = 192;
  int swz = (id & 7) * (nwg >> 3) + (id >> 3);
  int bx = swz % nbx, by = swz / nbx;

  f32x4 acc[8][4] = {};
  gemm8_core(A, BT, Dd, by * 256, bx * 256, As, Bs, acc);

  int lane = threadIdx.x & 63, wave = threadIdx.x >> 6;
  int wr = wave >> 2, wc = wave & 3;
  int m16 = lane & 15, quad = lane >> 4;
  int wcol = (wc >> 1) * 128 + (wc & 1) * 64;

  if (bx < 8) {           // ---- Q: rowmajor bf16, pre-scaled ----
    int colb = bx * 256 + wcol;
    #pragma unroll
    for (int nj = 0; nj < 4; ++nj) {
      int col = colb + nj * 16 + m16;
      float bc = bq[col];
      #pragma unroll
      for (int mi = 0; mi < 8; ++mi)
        #pragma unroll
        for (int rr = 0; rr < 4; ++rr) {
          int row = by * 256 + wr * 128 + mi * 16 + quad * 4 + rr;
          qb[(size_t)row * NQ + col] = f2bf((acc[mi][nj][rr] + bc) * (0.125f * LOG2E));
        }
    }
  } else if (bx < 10) {   // ---- K: rowmajor bf16 ----
    int colb = (bx - 8) * 256 + wcol;
    #pragma unroll
    for (int nj = 0; nj < 4; ++nj) {
      int col = colb + nj * 16 + m16;
      float bc = bk[col];
      #pragma unroll
      for (int mi = 0; mi < 8; ++mi)
        #pragma unroll
        for (int rr = 0; rr < 4; ++rr) {
          int row = by * 256 + wr * 128 + mi * 16 + quad * 4 + rr;
          kb[(size_t)row * NKV + col] = f2bf(acc[mi][nj][rr] + bc);
        }
    }
  } else {                // ---- V: transposed write vT[(b*512+col)][t] ----
    int colb = (bx - 10) * 256 + wcol;
    #pragma unroll
    for (int nj = 0; nj < 4; ++nj) {
      int col = colb + nj * 16 + m16;
      float bc = bv[col];
      #pragma unroll
      for (int mi = 0; mi < 8; ++mi) {
        int row = by * 256 + wr * 128 + mi * 16 + quad * 4;   // 4 consecutive t
        int b = row >> 11, t = row & 2047;
        ushort4 pk;
        pk.x = f2bf(acc[mi][nj][0] + bc);
        pk.y = f2bf(acc[mi][nj][1] + bc);
        pk.z = f2bf(acc[mi][nj][2] + bc);
        pk.w = f2bf(acc[mi][nj][3] + bc);
        *(ushort4*)(vT + ((size_t)(b * NKV + col)) * Ss + t) = pk;
      }
    }
  }
}

// ---------------------------------------------------------------------------
// Wo projection, 256M x 128N, same deepened schedule (6 loads/tile, vmcnt(6)).
// ---------------------------------------------------------------------------
__global__ __launch_bounds__(512) void gemm8_wo(
    const u16* __restrict__ A, const u16* __restrict__ BT,
    const float* __restrict__ bias, float* __restrict__ C, int N, int K)
{
  __shared__ u16 As[32768];   // 64 KB (2 x 256x64)
  __shared__ u16 Bs[16384];   // 32 KB (2 x 128x64)
  int nbx = N >> 7;                        // 16
  int id  = blockIdx.y * nbx + blockIdx.x;
  int nwg = gridDim.x * gridDim.y;         // 256
  int swz = (id & 7) * (nwg >> 3) + (id >> 3);
  int bx = swz % nbx, by = swz / nbx;

  const int tid  = threadIdx.x;
  const int lane = tid & 63;
  const int wave = tid >> 6;
  const int wr = wave >> 2, wc = wave & 3; // wr: M-half, wc: 32-col strip
  const int m16 = lane & 15, quad = lane >> 4;
  const int NT = K >> 6;

  const int r0 = tid >> 3;
  const int sg = (tid & 7) ^ (r0 & 7);
  const u16* Asrc = A  + (size_t)(by * 256 + r0) * K + sg * 8;
  const u16* Bsrc = BT + (size_t)(bx * 128 + r0) * K + sg * 8;
  u16* AsW = As + wave * 512;
  u16* BsW = Bs + wave * 512;
  const size_t a64  = (size_t)64 * K;
  const size_t a128 = (size_t)128 * K;

  const int sl0 = (quad ^ (m16 & 7)) * 8;
  const int sl1 = ((quad | 4) ^ (m16 & 7)) * 8;
  const u16* Afr = As + wr * 8192 + m16 * 64;
  const u16* Bfr = Bs + (wc * 32 + m16) * 64;

  f32x4 acc[8][2] = {};

  // prologue: tiles t0 and t1, 6 loads each (A.h0, A.h1, B)
  #pragma unroll
  for (int tt = 0; tt < 2; ++tt) {
    #pragma unroll
    for (int h = 0; h < 2; ++h) {
      gload16(Asrc + h * a128 + tt * 64,       AsW + tt * 16384 + h * 8192);
      gload16(Asrc + h * a128 + a64 + tt * 64, AsW + tt * 16384 + h * 8192 + 4096);
    }
    gload16(Bsrc + tt * 64,       BsW + tt * 8192);
    gload16(Bsrc + a64 + tt * 64, BsW + tt * 8192 + 4096);
  }
  WAITV6();   // t0's 6 landed; t1's 6 in flight
  BAR();

  for (int t = 0; t < NT; ++t) {
    const int bi = t & 1;
    const u16* Abuf = Afr + bi * 16384;
    const u16* Bbuf = Bfr + bi * 8192;
    const bool st = (t + 2 < NT);
    const u16* Ag2 = Asrc + (size_t)(t + 2) * 64;
    const u16* Bg2 = Bsrc + (size_t)(t + 2) * 64;
    u16* AsN = AsW + bi * 16384;
    u16* BsN = BsW + bi * 8192;

    s16x8 af[8][2], bfr[2][2];
    #pragma unroll
    for (int mi = 0; mi < 8; ++mi) {
      af[mi][0] = *(const s16x8*)(Abuf + mi * 1024 + sl0);
      af[mi][1] = *(const s16x8*)(Abuf + mi * 1024 + sl1);
    }
    #pragma unroll
    for (int nj = 0; nj < 2; ++nj) {
      bfr[nj][0] = *(const s16x8*)(Bbuf + nj * 1024 + sl0);
      bfr[nj][1] = *(const s16x8*)(Bbuf + nj * 1024 + sl1);
    }
    #pragma unroll
    for (int ph = 0; ph < 4; ++ph) {
      if (st) {
        if (ph == 1) {            // A(t+2).h0
          gload16(Ag2,       AsN);
          gload16(Ag2 + a64, AsN + 4096);
        } else if (ph == 2) {     // A(t+2).h1
          gload16(Ag2 + a128,       AsN + 8192);
          gload16(Ag2 + a128 + a64, AsN + 8192 + 4096);
        } else if (ph == 3) {     // B(t+2)
          gload16(Bg2,       BsN);
          gload16(Bg2 + a64, BsN + 4096);
        }
      }
      BAR();
      __builtin_amdgcn_s_setprio(1);
      #pragma unroll
      for (int nj = 0; nj < 2; ++nj) {
        acc[ph*2+0][nj] = __builtin_amdgcn_mfma_f32_16x16x32_bf16(af[ph*2+0][0], bfr[nj][0], acc[ph*2+0][nj], 0, 0, 0);
        acc[ph*2+0][nj] = __builtin_amdgcn_mfma_f32_16x16x32_bf16(af[ph*2+0][1], bfr[nj][1], acc[ph*2+0][nj], 0, 0, 0);
        acc[ph*2+1][nj] = __builtin_amdgcn_mfma_f32_16x16x32_bf16(af[ph*2+1][0], bfr[nj][0], acc[ph*2+1][nj], 0, 0, 0);
        acc[ph*2+1][nj] = __builtin_amdgcn_mfma_f32_16x16x32_bf16(af[ph*2+1][1], bfr[nj][1], acc[ph*2+1][nj], 0, 0, 0);
      }
      __builtin_amdgcn_s_setprio(0);
      if (ph == 0) LGKM0();
      if (ph == 3) {
        if (st) WAITV6(); else WAITV0();
      }
      BAR();
    }
  }

  int colb = bx * 128 + wc * 32;
  #pragma unroll
  for (int nj = 0; nj < 2; ++nj) {
    int col = colb + nj * 16 + m16;
    float bc = bias[col];
    #pragma unroll
    for (int mi = 0; mi < 8; ++mi)
      #pragma unroll
      for (int rr = 0; rr < 4; ++rr) {
        int row = by * 256 + wr * 128 + mi * 16 + quad * 4 + rr;
        C[(size_t)row * N + col] = acc[mi][nj][rr] + bc;
      }
  }
}

// ---------------------------------------------------------------------------
// Pass A: per-column softmax stats over the QUERY axis (base-2 domain).
// Writes cst NEGATED: cst[T] = -(m2 + log2 l).
// ---------------------------------------------------------------------------
__global__ __launch_bounds__(256) void pass_a_mfma(
    const u16* __restrict__ qb, const u16* __restrict__ kb,
    float* __restrict__ cst)
{
  __shared__ u16 Qs[2][64 * 64];   // 16 KB
  int combo = blockIdx.x;
  int qk = combo & 3, bh = combo >> 2;
  int b = bh >> 3, h = bh & 7;
  int g = blockIdx.y;                     // 0..15, longest first
  int tid = threadIdx.x;
  int lane = tid & 63, wave = tid >> 6;
  int m16 = lane & 15, quad = lane >> 4;
  int T0w = g * 128 + wave * 32;          // wave's 32 T-columns

  const u16* kbase = kb + (size_t)b * Ss * NKV + h * HD;
  const u16* qbase = qb + (size_t)b * Ss * NQ + (h * QPK + qk) * HD;

  s16x8 kf[2][2];   // B-operand frags (n=T), loaded once
  #pragma unroll
  for (int jg = 0; jg < 2; ++jg)
    #pragma unroll
    for (int dc = 0; dc < 2; ++dc)
      kf[jg][dc] = *(const s16x8*)(kbase + (size_t)(T0w + jg * 16 + m16) * NKV + dc * 32 + quad * 8);

  float ms[2] = {-1e30f, -1e30f};
  float ls[2] = {0.f, 0.f};
  int srow  = (wave << 3) + (lane >> 3);
  int slot0 = (lane & 7) ^ (lane >> 3);
  int sl0 = quad ^ (m16 & 7);
  int sl1 = (quad | 4) ^ (m16 & 7);
  int tDiag = T0w & ~63;

  // prologue: stage tile t0 = g*128 into Qs[0]
  {
    u16* QsW = &Qs[0][(wave * 8) * 64];
    int t0 = g * 128;
    gload16(qbase + (size_t)(t0 + srow) * NQ + slot0 * 8, QsW);
    gload16(qbase + (size_t)(t0 + srow + 32) * NQ + slot0 * 8, QsW + 32 * 64);
  }

  for (int t0 = g * 128; t0 < Ss; t0 += 64) {
    int cur = (t0 >> 6) & 1;
    bool nxt = (t0 + 64 < Ss);
    if (nxt) {
      u16* QsW = &Qs[cur ^ 1][(wave * 8) * 64];
      gload16(qbase + (size_t)(t0 + 64 + srow) * NQ + slot0 * 8, QsW);
      gload16(qbase + (size_t)(t0 + 64 + srow + 32) * NQ + slot0 * 8, QsW + 32 * 64);
      WAITV2();
    } else {
      WAITV0();
    }
    BAR();
    if (t0 + 63 < T0w) { BAR(); continue; }   // wave inactive; barriers matched

    const u16* Qc = &Qs[cur][0];
    s16x8 af[4][2];
    #pragma unroll
    for (int i = 0; i < 4; ++i) {
      af[i][0] = *(const s16x8*)(Qc + (i * 16 + m16) * 64 + sl0 * 8);
      af[i][1] = *(const s16x8*)(Qc + (i * 16 + m16) * 64 + sl1 * 8);
    }
    f32x4 acc[4][2];
    #pragma unroll
    for (int i = 0; i < 4; ++i)
      #pragma unroll
      for (int jg = 0; jg < 2; ++jg) {
        f32x4 z = {};
        z = __builtin_amdgcn_mfma_f32_16x16x32_bf16(af[i][0], kf[jg][0], z, 0, 0, 0);
        acc[i][jg] = __builtin_amdgcn_mfma_f32_16x16x32_bf16(af[i][1], kf[jg][1], z, 0, 0, 0);
      }
    if (t0 == tDiag) {   // diagonal block: mask t < T with very-low sentinel
      #pragma unroll
      for (int i = 0; i < 4; ++i)
        #pragma unroll
        for (int jg = 0; jg < 2; ++jg) {
          int tg = t0 + i * 16 + quad * 4;
          int Tg = T0w + jg * 16 + m16;
          #pragma unroll
          for (int r = 0; r < 4; ++r)
            if (tg + r < Tg) acc[i][jg][r] = -3e38f;
        }
    }
    #pragma unroll
    for (int jg = 0; jg < 2; ++jg) {
      float bm = -3e38f;
      #pragma unroll
      for (int i = 0; i < 4; ++i)
        #pragma unroll
        for (int r = 0; r < 4; ++r) bm = fmaxf(bm, acc[i][jg][r]);
      float mn = fmaxf(ms[jg], bm);
      float se = 0.f;
      #pragma unroll
      for (int i = 0; i < 4; ++i)
        #pragma unroll
        for (int r = 0; r < 4; ++r) se += exp2f(acc[i][jg][r] - mn);
      ls[jg] = ls[jg] * exp2f(ms[jg] - mn) + se;
      ms[jg] = mn;
    }
    BAR();
  }
  // cross-quad merge (cols live on m16; quads hold disjoint t-subsets)
  #pragma unroll
  for (int jg = 0; jg < 2; ++jg) {
    float m = ms[jg], l = ls[jg];
    #pragma unroll
    for (int off = 16; off <= 32; off <<= 1) {
      float mo = __shfl_xor(m, off);
      float lo = __shfl_xor(l, off);
      float mn = fmaxf(m, mo);
      l = l * exp2f(m - mn) + lo * exp2f(mo - mn);
      m = mn;
    }
    if (quad == 0)
      cst[(size_t)(bh * QPK + qk) * Ss + T0w + jg * 16 + m16] = -(m + __log2f(l));
  }
}

// ---------------------------------------------------------------------------
// Pass B: out[t,:] = sum_{T<=t} exp2(s2(t,T)+negc[T]) * v[T,:]
// K AND V double-buffered in LDS (counted vmcnt(4)); negc folded into the
// QK MFMA accumulator init.  P never touches LDS: cvt_pk + permlane swaps.
// ---------------------------------------------------------------------------
__global__ __launch_bounds__(256) void pass_b_mfma(
    const u16* __restrict__ qb, const u16* __restrict__ kb,
    const u16* __restrict__ vT, const float* __restrict__ cst,
    u16* __restrict__ attn)
{
  __shared__ u16 Ks[2][64 * 64];   // 16 KB
  __shared__ u16 Vs[2][64 * 64];   // 16 KB
  int combo = blockIdx.x;
  int qk = combo & 3, bh = combo >> 2;
  int b = bh >> 3, h = bh & 7;
  int g = 31 - blockIdx.y;                // longest first
  int tid = threadIdx.x;
  int lane = tid & 63, wave = tid >> 6;
  int m16 = lane & 15, quad = lane >> 4;
  int trow = g * 64 + wave * 16;          // wave's 16 t-rows

  const u16* qbase = qb + (size_t)b * Ss * NQ + (h * QPK + qk) * HD;
  const u16* kbase = kb + (size_t)b * Ss * NKV + h * HD;
  const u16* vbase = vT + (size_t)(bh * 64) * Ss;
  const float* cbase = cst + (size_t)(bh * QPK + qk) * Ss;

  s16x8 qf[2];   // B-operand (n=t) frags for this wave's rows
  #pragma unroll
  for (int dc = 0; dc < 2; ++dc)
    qf[dc] = *(const s16x8*)(qbase + (size_t)(trow + m16) * NQ + dc * 32 + quad * 8);

  f32x4 oacc[4] = {};   // C-layout: row t = quad*4+r, col d = dj*16+m16
  int srow  = (wave << 3) + (lane >> 3);
  int slot0 = (lane & 7) ^ (lane >> 3);
  int sl0 = quad ^ (m16 & 7);
  int sl1 = (quad | 4) ^ (m16 & 7);
  int Tend = g * 64;

  // prologue: stage K+V tile 0 into buf 0
  {
    u16* KsW = &Ks[0][(wave * 8) * 64];
    u16* VsW = &Vs[0][(wave * 8) * 64];
    gload16(kbase + (size_t)srow * NKV + slot0 * 8, KsW);
    gload16(kbase + (size_t)(srow + 32) * NKV + slot0 * 8, KsW + 32 * 64);
    gload16(vbase + (size_t)srow * Ss + slot0 * 8, VsW);
    gload16(vbase + (size_t)(srow + 32) * Ss + slot0 * 8, VsW + 32 * 64);
  }

  for (int T0 = 0; T0 <= Tend; T0 += 64) {
    int cur = (T0 >> 6) & 1;
    bool nxt = (T0 + 64 <= Tend);
    // negc loads for THIS tile -- issued before next-tile stage (ordering
    // matters: compiler's wait-for-cc then leaves the stage loads in flight)
    float4 cc[4];
    #pragma unroll
    for (int i = 0; i < 4; ++i)
      cc[i] = *(const float4*)(cbase + T0 + i * 16 + quad * 4);
    __builtin_amdgcn_sched_barrier(0);
    if (nxt) {
      u16* KsW = &Ks[cur ^ 1][(wave * 8) * 64];
      u16* VsW = &Vs[cur ^ 1][(wave * 8) * 64];
      gload16(kbase + (size_t)(T0 + 64 + srow) * NKV + slot0 * 8, KsW);
      gload16(kbase + (size_t)(T0 + 64 + srow + 32) * NKV + slot0 * 8, KsW + 32 * 64);
      gload16(vbase + (size_t)srow * Ss + T0 + 64 + slot0 * 8, VsW);
      gload16(vbase + (size_t)(srow + 32) * Ss + T0 + 64 + slot0 * 8, VsW + 32 * 64);
      WAITV4();   // drains prev stage + cc; leaves the 4 new stage loads
    } else {
      WAITV0();
    }
    BAR();
    bool diag = (T0 == Tend);
    const u16* Kc = &Ks[cur][0];
    const u16* Vc = &Vs[cur][0];
    // tc = T-chunk of 32 (PV k-dim); i = score T-row-block of 16
    #pragma unroll
    for (int tc = 0; tc < 2; ++tc) {
      u32 A[2], Bw[2];
      #pragma unroll
      for (int ii = 0; ii < 2; ++ii) {
        int i = tc * 2 + ii;
        s16x8 k0 = *(const s16x8*)(Kc + (i * 16 + m16) * 64 + sl0 * 8);
        s16x8 k1 = *(const s16x8*)(Kc + (i * 16 + m16) * 64 + sl1 * 8);
        float4 c4 = cc[i];
        f32x4 z = {c4.x, c4.y, c4.z, c4.w};   // acc-init = -c (pre-negated)
        z = __builtin_amdgcn_mfma_f32_16x16x32_bf16(k0, qf[0], z, 0, 0, 0);
        z = __builtin_amdgcn_mfma_f32_16x16x32_bf16(k1, qf[1], z, 0, 0, 0);
        float w0 = exp2f(z[0]);
        float w1 = exp2f(z[1]);
        float w2 = exp2f(z[2]);
        float w3 = exp2f(z[3]);
        if (diag) {
          int t  = trow + m16;
          int Tg = T0 + i * 16 + quad * 4;
          if (Tg + 0 > t) w0 = 0.f;
          if (Tg + 1 > t) w1 = 0.f;
          if (Tg + 2 > t) w2 = 0.f;
          if (Tg + 3 > t) w3 = 0.f;
        }
        A[ii]  = cvtpk_bf16(w0, w1);
        Bw[ii] = cvtpk_bf16(w2, w3);
      }
      // cross-quad redistribution: quads {0,1}->dest {0,2}, {2,3}->dest {1,3}
      asm volatile("v_permlane32_swap_b32 %0, %1" : "+v"(A[0]),  "+v"(A[1]));
      asm volatile("v_permlane16_swap_b32 %0, %1" : "+v"(A[0]),  "+v"(A[1]));
      asm volatile("v_permlane32_swap_b32 %0, %1" : "+v"(Bw[0]), "+v"(Bw[1]));
      asm volatile("v_permlane16_swap_b32 %0, %1" : "+v"(Bw[0]), "+v"(Bw[1]));
      union { uint4 u; s16x8 v; } pu;
      pu.u.x = A[0]; pu.u.y = Bw[0]; pu.u.z = A[1]; pu.u.w = Bw[1];
      s16x8 pa = pu.v;   // A-operand: P[t=m16][T = T0 + tc*32 + quad*8 + j]
      #pragma unroll
      for (int dj = 0; dj < 4; ++dj) {
        int vsl = (quad | (tc << 2)) ^ (m16 & 7);
        s16x8 vf = *(const s16x8*)(Vc + (dj * 16 + m16) * 64 + vsl * 8);
        oacc[dj] = __builtin_amdgcn_mfma_f32_16x16x32_bf16(pa, vf, oacc[dj], 0, 0, 0);
      }
    }
    BAR();
  }
  // ---- epilogue: attn (b, t, (h*QPK+qk)*64 + d) bf16 ----
  u16* abase = attn + (size_t)b * Ss * NQ + (h * QPK + qk) * HD;
  #pragma unroll
  for (int dj = 0; dj < 4; ++dj)
    #pragma unroll
    for (int r = 0; r < 4; ++r)
      abase[(size_t)(trow + quad * 4 + r) * NQ + dj * 16 + m16] = f2bf(oacc[dj][r]);
}

// ---------------------------------------------------------------------------
extern "C" void kernel_launch(void* const* d_in, const int* in_sizes, int n_in,
                              void* d_out, int out_size, void* d_ws, size_t ws_size,
                              hipStream_t stream)
{
  (void)in_sizes; (void)n_in; (void)out_size; (void)ws_size;
  const float* x   = (const float*)d_in[0];
  const float* lng = (const float*)d_in[1];
  const float* lnb = (const float*)d_in[2];
  const float* Wq  = (const float*)d_in[3];
  const float* bq  = (const float*)d_in[4];
  const float* Wk  = (const float*)d_in[5];
  const float* bk  = (const float*)d_in[6];
  const float* Wv  = (const float*)d_in[7];
  const float* bv  = (const float*)d_in[8];
  const float* Wo  = (const float*)d_in[9];
  const float* bo  = (const float*)d_in[10];
  float* out = (float*)d_out;

  char* ws = (char*)d_ws;
  size_t off = 0;
  auto take = [&](size_t bytes) -> char* {
    char* p = ws + off;
    off += (bytes + 255) & ~(size_t)255;
    return p;
  };
  u16*    xnb   = (u16*)take((size_t)MR * Dd * 2);             // 16 MB
  u16*    wqkvT = (u16*)take((size_t)(NQ + 2 * NKV) * Dd * 2); // 12 MB (Q;K;V rows)
  u16*    woT   = (u16*)take((size_t)Dd * NQ * 2);             // 8 MB
  u16*    qbB   = (u16*)take((size_t)MR * NQ * 2);             // 16 MB
  u16*    kbB   = (u16*)take((size_t)MR * NKV * 2);            // 4 MB
  u16*    vTb   = (u16*)take((size_t)MR * NKV * 2);            // 4 MB (transposed)
  float*  cst   = (float*)take((size_t)Bb * HKV * QPK * Ss * 4); // 0.5 MB
  u16*    attnb = (u16*)take((size_t)MR * NQ * 2);             // 16 MB

  ln_kernel<<<MR, 256, 0, stream>>>(x, lng, lnb, xnb);
  // all 4 weight transposes in one launch
  transpose_all<<<10240, 256, 0, stream>>>(Wq, Wk, Wv, Wo, wqkvT, woT);

  // fused Q/K/V projection (q pre-scaled; V written directly transposed)
  gemm8_qkv<<<dim3(12, 16), 512, 0, stream>>>(xnb, wqkvT, bq, bk, bv, qbB, kbB, vTb);

  pass_a_mfma<<<dim3(64, 16), 256, 0, stream>>>(qbB, kbB, cst);
  pass_b_mfma<<<dim3(64, 32), 256, 0, stream>>>(qbB, kbB, vTb, cst, attnb);

  gemm8_wo<<<dim3(16, 16), 512, 0, stream>>>(attnb, woT, bo, out, Dd, NQ);
}